// Round 4
// baseline (277.697 us; speedup 1.0000x reference)
//
#include <hip/hip_runtime.h>

typedef unsigned short u16;
typedef unsigned int u32;
typedef u16 u16x4 __attribute__((ext_vector_type(4)));
typedef u16 u16x8 __attribute__((ext_vector_type(8)));
typedef __bf16 bf16x8 __attribute__((ext_vector_type(8)));
typedef float f32x4 __attribute__((ext_vector_type(4)));

__device__ __forceinline__ u16 f2bf(float f) {
  union { float f; unsigned u; } c; c.f = f;
  unsigned u = c.u;
  return (u16)((u + 0x7fff + ((u >> 16) & 1)) >> 16);
}

// fast exp2: scores are bounded (|S| ~ 4), raw v_exp_f32 is safe (1 ULP)
__device__ __forceinline__ float fexp2(float x) {
  float r; asm("v_exp_f32 %0, %1" : "=v"(r) : "v"(x)); return r;
}

// pack two f32 -> bf16x2 in one instruction (T12 recipe; no builtin on gfx950)
__device__ __forceinline__ u32 cvtpk(float lo, float hi) {
  u32 r;
  asm("v_cvt_pk_bf16_f32 %0, %1, %2" : "=v"(r) : "v"(lo), "v"(hi));
  return r;
}

// async global->LDS, 16B per lane. LDS dest must be wave-uniform base + lane*16.
__device__ __forceinline__ void lds16(const u16* g, u16* l) {
  __builtin_amdgcn_global_load_lds(
      (const __attribute__((address_space(1))) unsigned int*)g,
      (__attribute__((address_space(3))) unsigned int*)l, 16, 0, 0);
}

// SCALE = (1280//8)^-0.5, folded with log2(e); baked into Q-projection weights
#define CEXP (0.07905694150420949f * 1.4426950408889634f)

#define BAR()  do { asm volatile("" ::: "memory"); \
                    __builtin_amdgcn_s_barrier(); \
                    asm volatile("" ::: "memory"); } while (0)
#define VMC(n) asm volatile("s_waitcnt vmcnt(" #n ")" ::: "memory")

// ---------------------------------------------------------------------------
// combined prep: Wd cast | Wqkv^T (+CEXP on Q rows) | Wup^T | x -> bf16
// ---------------------------------------------------------------------------
#define PREP_W (1280 * 256 + 768 * 256 + 1280 * 256)   // 851968 weight elems

__global__ __launch_bounds__(256)
void prep_all(const float* __restrict__ Wd, const float* __restrict__ Wqkv,
              const float* __restrict__ Wup, const float* __restrict__ X,
              u16* __restrict__ WdC, u16* __restrict__ WqkvT,
              u16* __restrict__ WupT, u16* __restrict__ Xb, int n8) {
  int id = blockIdx.x * 256 + threadIdx.x;
  if (id < 1280 * 256) {                      // straight cast of Wd
    WdC[id] = f2bf(Wd[id]);
    return;
  }
  id -= 1280 * 256;
  if (id < 768 * 256) {                       // Wqkv^T, scale Q rows by CEXP
    int n = id >> 8, c = id & 255;
    float v = Wqkv[(size_t)c * 768 + n];
    if (n < 256) v *= CEXP;
    WqkvT[id] = f2bf(v);
    return;
  }
  id -= 768 * 256;
  if (id < 1280 * 256) {                      // Wup^T
    int n = id >> 8, c = id & 255;
    WupT[id] = f2bf(Wup[(size_t)c * 1280 + n]);
    return;
  }
  id -= 1280 * 256;
  if (id < n8) {                              // x -> bf16, 8 elems/thread
    const float4* src = (const float4*)(X + (size_t)id * 8);
    float4 lo = src[0], hi = src[1];
    u16x8 v;
    v[0]=f2bf(lo.x); v[1]=f2bf(lo.y); v[2]=f2bf(lo.z); v[3]=f2bf(lo.w);
    v[4]=f2bf(hi.x); v[5]=f2bf(hi.y); v[6]=f2bf(hi.z); v[7]=f2bf(hi.w);
    *(u16x8*)(Xb + (size_t)id * 8) = v;
  }
}

// ---------------------------------------------------------------------------
// GEMM: C[M,N] = A[M,K] * BT[N,K]^T (+bias). m97 structure + content-XOR
// LDS swizzle. 128x128 tile, 4 waves of 64x64, BK=64. Used for the small
// WpT GEMM and the AF32 fallback.
// ---------------------------------------------------------------------------
template <int AF32>
__global__ __launch_bounds__(256)
void gemm_bt(const void* __restrict__ Av,
             const u16* __restrict__ BT,
             u16* __restrict__ Cb, float* __restrict__ Cf,
             const float* __restrict__ bias,
             int M, int N, int K)
{
  __shared__ u16 As[128][64];
  __shared__ u16 Bs[128][64];
  const int tid  = threadIdx.x;
  const int wave = tid >> 6, lane = tid & 63;
  const int quad = lane >> 4, l16 = lane & 15;
  const int rsw  = l16 & 7;                 // read-side row XOR
  const int ssw  = ((lane & 7) ^ (lane >> 3)) << 3;  // staging col (pre-swz)

  const int nb = N >> 7, mb = M >> 7;
  int band, nblk;
  if ((mb & 7) == 0) {
    int xcd = blockIdx.x & 7, slot = blockIdx.x >> 3;
    band = xcd + 8 * (slot / nb);
    nblk = slot % nb;
  } else {
    band = blockIdx.x / nb;
    nblk = blockIdx.x % nb;
  }
  const int m0 = band * 128, n0 = nblk * 128;
  const int wr = (wave >> 1) * 64, wc = (wave & 1) * 64;
  const u16*   A16 = (const u16*)Av;
  const float* A32 = (const float*)Av;

  f32x4 acc[4][4];
#pragma unroll
  for (int i = 0; i < 4; i++)
#pragma unroll
    for (int j = 0; j < 4; j++) acc[i][j] = f32x4{0.f, 0.f, 0.f, 0.f};

  for (int k0 = 0; k0 < K; k0 += 64) {
    if constexpr (AF32) {
#pragma unroll
      for (int it = 0; it < 4; it++) {
        int idx = tid + it * 256;
        int r = idx >> 3;
        const float* src = &A32[(size_t)(m0 + r) * K + k0 + ((idx & 7) << 3)];
        float4 lo = *(const float4*)src;
        float4 hi = *(const float4*)(src + 4);
        u16x8 v;
        v[0]=f2bf(lo.x); v[1]=f2bf(lo.y); v[2]=f2bf(lo.z); v[3]=f2bf(lo.w);
        v[4]=f2bf(hi.x); v[5]=f2bf(hi.y); v[6]=f2bf(hi.z); v[7]=f2bf(hi.w);
        *(u16x8*)&As[r][((idx & 7) ^ (r & 7)) << 3] = v;
      }
#pragma unroll
      for (int it = 0; it < 4; it++) {
        int r0 = wave * 32 + it * 8;
        lds16(&BT[(size_t)(n0 + r0 + (lane >> 3)) * K + k0 + ssw],
              &Bs[r0][0] + lane * 8);
      }
    } else {
#pragma unroll
      for (int it = 0; it < 4; it++) {
        int r0 = wave * 32 + it * 8;
        lds16(&A16[(size_t)(m0 + r0 + (lane >> 3)) * K + k0 + ssw],
              &As[r0][0] + lane * 8);
        lds16(&BT[(size_t)(n0 + r0 + (lane >> 3)) * K + k0 + ssw],
              &Bs[r0][0] + lane * 8);
      }
    }
    __syncthreads();
#pragma unroll
    for (int ks = 0; ks < 64; ks += 32) {
      bf16x8 af[4], bfr[4];
#pragma unroll
      for (int i = 0; i < 4; i++)
        af[i] = *(const bf16x8*)&As[wr + i * 16 + l16][(((ks >> 3) + quad) ^ rsw) << 3];
#pragma unroll
      for (int j = 0; j < 4; j++)
        bfr[j] = *(const bf16x8*)&Bs[wc + j * 16 + l16][(((ks >> 3) + quad) ^ rsw) << 3];
#pragma unroll
      for (int i = 0; i < 4; i++)
#pragma unroll
        for (int j = 0; j < 4; j++)
          acc[i][j] = __builtin_amdgcn_mfma_f32_16x16x32_bf16(af[i], bfr[j], acc[i][j], 0, 0, 0);
    }
    __syncthreads();
  }

  // epilogue: C/D layout col=lane&15, row=quad*4+reg
#pragma unroll
  for (int i = 0; i < 4; i++) {
#pragma unroll
    for (int j = 0; j < 4; j++) {
      int col = n0 + wc + j * 16 + l16;
      float bv = bias ? bias[col] : 0.0f;
#pragma unroll
      for (int r = 0; r < 4; r++) {
        int row = m0 + wr + i * 16 + quad * 4 + r;
        float v = acc[i][j][r] + bv;
        if (Cf) Cf[(size_t)row * N + col] = v;
        else    Cb[(size_t)row * N + col] = f2bf(v);
      }
    }
  }
}

// ---------------------------------------------------------------------------
// Big-GEMM, 8-phase schedule (T2+T3+T4+T5 port of the m201 template):
// 256x256 tile, 512 threads (8 waves 2Mx4N, wave tile 128x64), BK=64,
// 2 dbuf x 2 half-slots per matrix (128 KiB LDS). Counted vmcnt(2) at
// phases 4/8 only. F32OUT adds bias + f32 store for the final projection.
// ---------------------------------------------------------------------------
#define LDA_(d, ib) { _Pragma("unroll") for (int i = 0; i < 4; i++) \
  _Pragma("unroll") for (int ks = 0; ks < 2; ks++) \
    af[i*2+ks] = *(const bf16x8*)&As[d][wm][(ib+i)*16 + l16][((ks*4+quad) ^ rsw) << 3]; }

#define LDB_(d, dst, jp) { _Pragma("unroll") for (int j = 0; j < 2; j++) \
  _Pragma("unroll") for (int ks = 0; ks < 2; ks++) \
    dst[j*2+ks] = *(const bf16x8*)&Bs[d][bh][br + (jp*2+j)*16 + l16][((ks*4+quad) ^ rsw) << 3]; }

#define MM_(ib, jp, breg) { __builtin_amdgcn_s_setprio(1); \
  _Pragma("unroll") for (int i = 0; i < 4; i++) \
  _Pragma("unroll") for (int j = 0; j < 2; j++) \
  _Pragma("unroll") for (int ks = 0; ks < 2; ks++) \
    acc[ib+i][jp*2+j] = __builtin_amdgcn_mfma_f32_16x16x32_bf16( \
        af[i*2+ks], breg[j*2+ks], acc[ib+i][jp*2+j], 0, 0, 0); \
  __builtin_amdgcn_s_setprio(0); }

template <int F32OUT>
__global__ __launch_bounds__(512, 2)
void gemm_bt256(const u16* __restrict__ A16, const u16* __restrict__ BT,
                u16* __restrict__ Cb, float* __restrict__ Cf,
                const float* __restrict__ bias, int M, int N, int K)
{
  __shared__ __align__(16) u16 As[2][2][128][64];  // [dbuf][half][row][col]
  __shared__ __align__(16) u16 Bs[2][2][128][64];
  const int tid  = threadIdx.x;
  const int wave = tid >> 6, lane = tid & 63;
  const int quad = lane >> 4, l16 = lane & 15;
  const int wm = wave >> 2, wn = wave & 3;   // 2 x 4 wave grid
  const int bh = wn >> 1, br = (wn & 1) * 64;
  const int rsw = l16 & 7;

  const int nb = N >> 8, mb = M >> 8;
  int band, nblk;
  if ((mb & 7) == 0) {
    int xcd = blockIdx.x & 7, slot = blockIdx.x >> 3;
    band = xcd + 8 * (slot / nb);
    nblk = slot % nb;
  } else {
    band = blockIdx.x / nb;
    nblk = blockIdx.x % nb;
  }
  const int m0 = band * 256, n0 = nblk * 256;
  const int NT = K >> 6;                     // 64-wide K tiles (even, >=4)

  const int srow = tid >> 3;                 // 0..63
  const int scol = ((tid & 7) ^ (srow & 7)) << 3;  // pre-swizzled global col

  auto stageA = [&](int t, int h) {
    const int d = t & 1;
    const size_t g = (size_t)(m0 + h * 128 + srow) * K + (t << 6) + scol;
    lds16(&A16[g], &As[d][h][0][0] + tid * 8);
    lds16(&A16[g + (size_t)64 * K], &As[d][h][64][0] + tid * 8);
  };
  auto stageB = [&](int t, int h) {
    const int d = t & 1;
    const size_t g = (size_t)(n0 + h * 128 + srow) * K + (t << 6) + scol;
    lds16(&BT[g], &Bs[d][h][0][0] + tid * 8);
    lds16(&BT[g + (size_t)64 * K], &Bs[d][h][64][0] + tid * 8);
  };

  bf16x8 af[8], b0[4], b1[4];
  f32x4 acc[8][4];
#pragma unroll
  for (int i = 0; i < 8; i++)
#pragma unroll
    for (int j = 0; j < 4; j++) acc[i][j] = f32x4{0.f, 0.f, 0.f, 0.f};

  // prologue: tile0 complete + tile1 A-half0
  stageA(0, 0); stageA(0, 1); stageB(0, 0); stageB(0, 1); stageA(1, 0);
  VMC(2);
  BAR();

  const int nIter = NT >> 1;
  for (int it = 0; it < nIter; ++it) {
    const int t0 = it * 2, t1 = t0 + 1;
    const bool more  = (t0 + 2 < NT);
    const bool more1 = (t1 + 2 < NT);

    // ---- dbuf0 (tile t0) ----
    LDA_(0, 0); LDB_(0, b0, 0);
    stageA(t1, 1);
    BAR(); MM_(0, 0, b0); BAR();
    LDB_(0, b1, 1);
    stageB(t1, 0);
    BAR(); MM_(0, 1, b1); BAR();
    LDA_(0, 4);
    stageB(t1, 1);
    BAR(); MM_(4, 1, b1); BAR();
    if (more) stageA(t0 + 2, 0);
    BAR(); MM_(4, 0, b0);
    if (more) { VMC(2); } else { VMC(0); }
    BAR();

    // ---- dbuf1 (tile t1) ----
    LDA_(1, 0); LDB_(1, b0, 0);
    if (more) stageA(t0 + 2, 1);
    BAR(); MM_(0, 0, b0); BAR();
    LDB_(1, b1, 1);
    if (more) stageB(t0 + 2, 0);
    BAR(); MM_(0, 1, b1); BAR();
    LDA_(1, 4);
    if (more) stageB(t0 + 2, 1);
    BAR(); MM_(4, 1, b1); BAR();
    if (more1) stageA(t1 + 2, 0);
    BAR(); MM_(4, 0, b0);
    if (it + 1 < nIter) {
      if (more1) { VMC(2); } else { VMC(0); }
      BAR();
    }
  }

  // epilogue: C/D layout col=lane&15, row=quad*4+reg
#pragma unroll
  for (int i = 0; i < 8; i++) {
#pragma unroll
    for (int j = 0; j < 4; j++) {
      const int col = n0 + wn * 64 + j * 16 + l16;
      float bv = F32OUT ? bias[col] : 0.0f;
#pragma unroll
      for (int r = 0; r < 4; r++) {
        const int row = m0 + wm * 128 + i * 16 + quad * 4 + r;
        if constexpr (F32OUT) Cf[(size_t)row * N + col] = acc[i][j][r] + bv;
        else                  Cb[(size_t)row * N + col] = f2bf(acc[i][j][r]);
      }
    }
  }
}

// ---------------------------------------------------------------------------
// One-shot V transpose with PV-fragment key permutation baked in:
// within each 32-key block, output slot s holds key perm(s) =
// (s>>3)*4 + (s&3) + 16*((s>>2)&1)  -- this matches the lane-local layout
// of P after the S^T QK^T, so attention builds its PV A-fragment entirely
// in-register (no P LDS round-trip). MFMA contraction is invariant under a
// key permutation applied to both operands.
// ---------------------------------------------------------------------------
__global__ __launch_bounds__(256)
void vtrans(const u16* __restrict__ qkv, u16* __restrict__ vT)
{
  __shared__ u16 T[32][72];
  const int tid   = threadIdx.x;
  const int kt    = blockIdx.x;        // 0..15 : 64-token tile
  const int head  = blockIdx.y >> 2;   // 0..7
  const int chunk = blockIdx.y & 3;    // 0..3
  const int b     = blockIdx.z;        // 0..3
  const size_t rowbase = (size_t)b * 4096 + chunk * 1024 + kt * 64;

  const int tok = tid >> 2;            // 0..63
  const int d8  = (tid & 3) << 3;      // 0,8,16,24
  u16x8 vv = *(const u16x8*)&qkv[(rowbase + tok) * 768 + 512 + head * 32 + d8];
  const int rot = (tok + (d8 >> 3)) & 7;
#pragma unroll
  for (int jj = 0; jj < 8; jj++) {
    int j = (jj + rot) & 7;
    T[d8 + j][tok] = vv[j];
  }
  __syncthreads();
  const int d = tid >> 3;              // 0..31
  const int s = tid & 7;               // output slot-group (8 keys)
  const int base = ((s >> 2) << 5) + ((s & 3) << 2);   // b32*32 + quad*4
  u16x4 lo = *(const u16x4*)&T[d][base];        // keys quad*4 + 0..3
  u16x4 hi = *(const u16x4*)&T[d][base + 16];   // keys quad*4 + 16..19
  u16x8 o8;
  o8[0]=lo[0]; o8[1]=lo[1]; o8[2]=lo[2]; o8[3]=lo[3];
  o8[4]=hi[0]; o8[5]=hi[1]; o8[6]=hi[2]; o8[7]=hi[3];
  size_t obase = ((size_t)((b * 4 + chunk) * 8 + head)) * 32768
               + (size_t)d * 1024 + kt * 64 + s * 8;
  *(u16x8*)&vT[obase] = o8;
}

// ---------------------------------------------------------------------------
// Block-diagonal attention. Q pre-scaled by SCALE*log2e in the projection.
// K and V^T staged via global_load_lds DMA into a 4-buffer ring, 2 tiles
// ahead, counted vmcnt(2) per iteration (never drained to 0 until tail).
// P never touches LDS: the PV A-fragment is lane-local thanks to vtrans's
// baked key permutation (pack via v_cvt_pk_bf16_f32 only).
// ---------------------------------------------------------------------------
__global__ __launch_bounds__(256)
void attn_kernel(const u16* __restrict__ qkv, const u16* __restrict__ vT,
                 u16* __restrict__ o)
{
  __shared__ __align__(16) u16 Ks[4][64][32];    // keys [key][d]
  __shared__ __align__(16) u16 VTs[4][32][64];   // V^T [d][key-slot] (swz)

  const int tid  = threadIdx.x;
  const int wave = tid >> 6, lane = tid & 63;
  const int quad = lane >> 4, l16 = lane & 15;
  const int qb    = blockIdx.x;        // 0..7
  const int head  = blockIdx.y >> 2;   // 0..7
  const int chunk = blockIdx.y & 3;    // 0..3
  const int b     = blockIdx.z;        // 0..3
  const size_t rowbase = (size_t)b * 4096 + chunk * 1024;
  const int tok0 = qb * 128 + wave * 32;

  const int kkey = tid >> 2;                     // 0..63
  const int kd8  = (tid & 3) << 3;               // 0,8,16,24
  const int vr   = tid >> 3;                     // d row 0..31
  const int vs   = tid & 7;                      // LDS slot'
  const int vsl  = (vs ^ (vr & 7)) << 3;         // content offset (XOR swz)
  const size_t vbase = ((size_t)((b * 4 + chunk) * 8 + head)) * 32768
                     + (size_t)vr * 1024 + vsl;

  auto stageKV = [&](int kb, int buf) {
    lds16(&qkv[(rowbase + kb * 64 + kkey) * 768 + 256 + head * 32 + kd8],
          &Ks[buf][0][0] + tid * 8);
    lds16(&vT[vbase + (size_t)kb * 64], &VTs[buf][0][0] + tid * 8);
  };

  stageKV(0, 0);

  bf16x8 qf[2];
#pragma unroll
  for (int qt = 0; qt < 2; qt++)
    qf[qt] = *(const bf16x8*)&qkv[(rowbase + tok0 + qt * 16 + l16) * 768 + head * 32 + quad * 8];

  stageKV(1, 1);

  float lsum[2] = {0.f, 0.f};
  f32x4 Oacc[2][2];
#pragma unroll
  for (int qt = 0; qt < 2; qt++)
#pragma unroll
    for (int nd = 0; nd < 2; nd++) Oacc[qt][nd] = f32x4{0.f, 0.f, 0.f, 0.f};

  VMC(2);          // buf0 landed (stage(1) may stay in flight)
  BAR();

  for (int kb = 0; kb < 16; kb++) {
    const int cur = kb & 3;
    if (kb + 2 < 16) stageKV(kb + 2, (kb + 2) & 3);

    bf16x8 kf[4];
#pragma unroll
    for (int kt = 0; kt < 4; kt++)
      kf[kt] = *(const bf16x8*)&Ks[cur][kt * 16 + l16][quad * 8];

    f32x4 ST[4][2];
    __builtin_amdgcn_s_setprio(1);
#pragma unroll
    for (int kt = 0; kt < 4; kt++)
#pragma unroll
      for (int qt = 0; qt < 2; qt++)
        ST[kt][qt] = __builtin_amdgcn_mfma_f32_16x16x32_bf16(kf[kt], qf[qt], f32x4{0.f,0.f,0.f,0.f}, 0, 0, 0);
    __builtin_amdgcn_s_setprio(0);

    // softmax weights, packed lane-locally (no LDS round-trip)
    u32 pw[2][4][2];
#pragma unroll
    for (int qt = 0; qt < 2; qt++)
#pragma unroll
      for (int kt = 0; kt < 4; kt++) {
        float p0 = fexp2(ST[kt][qt][0]);
        float p1 = fexp2(ST[kt][qt][1]);
        float p2 = fexp2(ST[kt][qt][2]);
        float p3 = fexp2(ST[kt][qt][3]);
        lsum[qt] += (p0 + p1) + (p2 + p3);
        pw[qt][kt][0] = cvtpk(p0, p1);
        pw[qt][kt][1] = cvtpk(p2, p3);
      }

#pragma unroll
    for (int ks = 0; ks < 2; ks++) {
      bf16x8 vf[2];
#pragma unroll
      for (int nd = 0; nd < 2; nd++)
        vf[nd] = *(const bf16x8*)&VTs[cur][nd * 16 + l16][((ks * 4 + quad) ^ (l16 & 7)) << 3];
      __builtin_amdgcn_s_setprio(1);
#pragma unroll
      for (int qt = 0; qt < 2; qt++) {
        union { u32 w[4]; bf16x8 v; } pu;
        pu.w[0] = pw[qt][2 * ks][0];
        pu.w[1] = pw[qt][2 * ks][1];
        pu.w[2] = pw[qt][2 * ks + 1][0];
        pu.w[3] = pw[qt][2 * ks + 1][1];
#pragma unroll
        for (int nd = 0; nd < 2; nd++)
          Oacc[qt][nd] = __builtin_amdgcn_mfma_f32_16x16x32_bf16(pu.v, vf[nd], Oacc[qt][nd], 0, 0, 0);
      }
      __builtin_amdgcn_s_setprio(0);
    }

    if (kb < 15) {
      if (kb + 2 < 16) { VMC(2); } else { VMC(0); }
      BAR();
    }
  }

#pragma unroll
  for (int qt = 0; qt < 2; qt++) {
    float s = lsum[qt];
    s += __shfl_xor(s, 16);
    s += __shfl_xor(s, 32);
    lsum[qt] = s;
  }
#pragma unroll
  for (int qt = 0; qt < 2; qt++)
#pragma unroll
    for (int r = 0; r < 4; r++) {
      float inv = 1.0f / __shfl(lsum[qt], quad * 4 + r, 16);
      size_t row = rowbase + tok0 + qt * 16 + quad * 4 + r;
#pragma unroll
      for (int nd = 0; nd < 2; nd++) {
        int col = head * 32 + nd * 16 + l16;
        o[row * 256 + col] = f2bf(Oacc[qt][nd][r] * inv);
      }
    }
}

// ---------------------------------------------------------------------------
extern "C" void kernel_launch(void* const* d_in, const int* in_sizes, int n_in,
                              void* d_out, int out_size, void* d_ws, size_t ws_size,
                              hipStream_t stream)
{
  const float* x    = (const float*)d_in[0];
  const float* Wd   = (const float*)d_in[1];
  const float* Wqkv = (const float*)d_in[2];
  const float* Wup  = (const float*)d_in[3];
  const float* bup  = (const float*)d_in[4];
  float* out = (float*)d_out;

  const int M = 4 * 4096;  // 16384 tokens

  // workspace (u16 elems): WdC | WqkvT | WupT | WpT | qkv | ob | xb(optional)
  u16* WdC   = (u16*)d_ws;              // Wd cast      [1280][256]
  u16* WqkvT = WdC   + 1280 * 256;      // Wqkv^T       [768][256] (Q rows *CEXP)
  u16* WupT  = WqkvT + 768 * 256;       // Wup^T        [1280][256]
  u16* WpT   = WupT  + 1280 * 256;      // (Wd@Wqkv)^T  [768][1280]
  u16* qkv   = WpT   + 768 * 1280;      // [16384][768]
  u16* ob    = qkv   + (size_t)M * 768; // [16384][256]
  u16* xb    = ob    + (size_t)M * 256; // [16384][1280] bf16 cast of x
  // vT aliases xb: xb is dead after the qkv GEMM; vtrans runs after it.
  u16* vT    = xb;                      // [128][32][1024] V transposed (perm'd)

  const size_t need = ((size_t)(1280*256 + 768*256 + 1280*256 + 768*1280)
                       + (size_t)M * (768 + 256 + 1280)) * sizeof(u16);
  const bool use_xb = ws_size >= need;  // ws_size constant across calls

  const int n8 = use_xb ? (M * 1280 / 8) : 0;
  prep_all<<<(PREP_W + n8 + 255) / 256, 256, 0, stream>>>(
      Wd, Wqkv, Wup, x, WdC, WqkvT, WupT, xb, n8);

  // W'^T[n][k] = sum_c WqkvT[n][c] * Wd[k][c]  -> [768][1280] bf16
  gemm_bt<0><<<dim3((1280 / 128) * (768 / 128)), 256, 0, stream>>>(
      (const void*)WqkvT, WdC, WpT, nullptr, nullptr, 768, 1280, 256);

  if (use_xb) {
    gemm_bt256<0><<<dim3((768 / 256) * (M / 256)), 512, 0, stream>>>(
        xb, WpT, qkv, nullptr, nullptr, M, 768, 1280);
  } else {
    gemm_bt<1><<<dim3((768 / 128) * (M / 128)), 256, 0, stream>>>(
        (const void*)x, WpT, qkv, nullptr, nullptr, M, 768, 1280);
  }

  // one-shot V transpose (writes over the dead xb region)
  vtrans<<<dim3(16, 32, 4), 256, 0, stream>>>(qkv, vT);

  // block-diagonal attention
  attn_kernel<<<dim3(8, 32, 4), 256, 0, stream>>>(qkv, vT, ob);

  // out = o @ Wup + bup (f32 out), 8-phase 256^2 path
  gemm_bt256<1><<<dim3((1280 / 256) * (M / 256)), 512, 0, stream>>>(
      ob, WupT, nullptr, out, bup, M, 1280, 256);
}

// Round 5
// 273.896 us; speedup vs baseline: 1.0139x; 1.0139x over previous
//
#include <hip/hip_runtime.h>

typedef unsigned short u16;
typedef unsigned int u32;
typedef u16 u16x4 __attribute__((ext_vector_type(4)));
typedef u16 u16x8 __attribute__((ext_vector_type(8)));
typedef __bf16 bf16x8 __attribute__((ext_vector_type(8)));
typedef float f32x4 __attribute__((ext_vector_type(4)));

__device__ __forceinline__ u16 f2bf(float f) {
  union { float f; unsigned u; } c; c.f = f;
  unsigned u = c.u;
  return (u16)((u + 0x7fff + ((u >> 16) & 1)) >> 16);
}

// fast exp2: scores are bounded (|S| ~ 4), raw v_exp_f32 is safe (1 ULP)
__device__ __forceinline__ float fexp2(float x) {
  float r; asm("v_exp_f32 %0, %1" : "=v"(r) : "v"(x)); return r;
}

// pack two f32 -> bf16x2 in one instruction (T12 recipe; no builtin on gfx950)
__device__ __forceinline__ u32 cvtpk(float lo, float hi) {
  u32 r;
  asm("v_cvt_pk_bf16_f32 %0, %1, %2" : "=v"(r) : "v"(lo), "v"(hi));
  return r;
}

// async global->LDS, 16B per lane. LDS dest must be wave-uniform base + lane*16.
__device__ __forceinline__ void lds16(const u16* g, u16* l) {
  __builtin_amdgcn_global_load_lds(
      (const __attribute__((address_space(1))) unsigned int*)g,
      (__attribute__((address_space(3))) unsigned int*)l, 16, 0, 0);
}

// SCALE = (1280//8)^-0.5, folded with log2(e); baked into Q-projection weights
#define CEXP (0.07905694150420949f * 1.4426950408889634f)

#define BAR()  do { asm volatile("" ::: "memory"); \
                    __builtin_amdgcn_s_barrier(); \
                    asm volatile("" ::: "memory"); } while (0)
#define VMC(n) asm volatile("s_waitcnt vmcnt(" #n ")" ::: "memory")

// ---------------------------------------------------------------------------
// combined prep: Wd cast | Wqkv^T (+CEXP on Q rows) | Wup^T | x -> bf16
// ---------------------------------------------------------------------------
#define PREP_W (1280 * 256 + 768 * 256 + 1280 * 256)   // 851968 weight elems

__global__ __launch_bounds__(256)
void prep_all(const float* __restrict__ Wd, const float* __restrict__ Wqkv,
              const float* __restrict__ Wup, const float* __restrict__ X,
              u16* __restrict__ WdC, u16* __restrict__ WqkvT,
              u16* __restrict__ WupT, u16* __restrict__ Xb, int n8) {
  int id = blockIdx.x * 256 + threadIdx.x;
  if (id < 1280 * 256) {                      // straight cast of Wd
    WdC[id] = f2bf(Wd[id]);
    return;
  }
  id -= 1280 * 256;
  if (id < 768 * 256) {                       // Wqkv^T, scale Q rows by CEXP
    int n = id >> 8, c = id & 255;
    float v = Wqkv[(size_t)c * 768 + n];
    if (n < 256) v *= CEXP;
    WqkvT[id] = f2bf(v);
    return;
  }
  id -= 768 * 256;
  if (id < 1280 * 256) {                      // Wup^T
    int n = id >> 8, c = id & 255;
    WupT[id] = f2bf(Wup[(size_t)c * 1280 + n]);
    return;
  }
  id -= 1280 * 256;
  if (id < n8) {                              // x -> bf16, 8 elems/thread
    const float4* src = (const float4*)(X + (size_t)id * 8);
    float4 lo = src[0], hi = src[1];
    u16x8 v;
    v[0]=f2bf(lo.x); v[1]=f2bf(lo.y); v[2]=f2bf(lo.z); v[3]=f2bf(lo.w);
    v[4]=f2bf(hi.x); v[5]=f2bf(hi.y); v[6]=f2bf(hi.z); v[7]=f2bf(hi.w);
    *(u16x8*)(Xb + (size_t)id * 8) = v;
  }
}

// ---------------------------------------------------------------------------
// GEMM: C[M,N] = A[M,K] * BT[N,K]^T (+bias). m97 structure + content-XOR
// LDS swizzle. 128x128 tile, 4 waves of 64x64, BK=64. Used for the small
// WpT GEMM, the final f32-out projection, and the AF32 fallback.
// ---------------------------------------------------------------------------
template <int AF32>
__global__ __launch_bounds__(256)
void gemm_bt(const void* __restrict__ Av,
             const u16* __restrict__ BT,
             u16* __restrict__ Cb, float* __restrict__ Cf,
             const float* __restrict__ bias,
             int M, int N, int K)
{
  __shared__ u16 As[128][64];
  __shared__ u16 Bs[128][64];
  const int tid  = threadIdx.x;
  const int wave = tid >> 6, lane = tid & 63;
  const int quad = lane >> 4, l16 = lane & 15;
  const int rsw  = l16 & 7;                 // read-side row XOR
  const int ssw  = ((lane & 7) ^ (lane >> 3)) << 3;  // staging col (pre-swz)

  const int nb = N >> 7, mb = M >> 7;
  int band, nblk;
  if ((mb & 7) == 0) {
    int xcd = blockIdx.x & 7, slot = blockIdx.x >> 3;
    band = xcd + 8 * (slot / nb);
    nblk = slot % nb;
  } else {
    band = blockIdx.x / nb;
    nblk = blockIdx.x % nb;
  }
  const int m0 = band * 128, n0 = nblk * 128;
  const int wr = (wave >> 1) * 64, wc = (wave & 1) * 64;
  const u16*   A16 = (const u16*)Av;
  const float* A32 = (const float*)Av;

  f32x4 acc[4][4];
#pragma unroll
  for (int i = 0; i < 4; i++)
#pragma unroll
    for (int j = 0; j < 4; j++) acc[i][j] = f32x4{0.f, 0.f, 0.f, 0.f};

  for (int k0 = 0; k0 < K; k0 += 64) {
    if constexpr (AF32) {
#pragma unroll
      for (int it = 0; it < 4; it++) {
        int idx = tid + it * 256;
        int r = idx >> 3;
        const float* src = &A32[(size_t)(m0 + r) * K + k0 + ((idx & 7) << 3)];
        float4 lo = *(const float4*)src;
        float4 hi = *(const float4*)(src + 4);
        u16x8 v;
        v[0]=f2bf(lo.x); v[1]=f2bf(lo.y); v[2]=f2bf(lo.z); v[3]=f2bf(lo.w);
        v[4]=f2bf(hi.x); v[5]=f2bf(hi.y); v[6]=f2bf(hi.z); v[7]=f2bf(hi.w);
        *(u16x8*)&As[r][((idx & 7) ^ (r & 7)) << 3] = v;
      }
#pragma unroll
      for (int it = 0; it < 4; it++) {
        int r0 = wave * 32 + it * 8;
        lds16(&BT[(size_t)(n0 + r0 + (lane >> 3)) * K + k0 + ssw],
              &Bs[r0][0] + lane * 8);
      }
    } else {
#pragma unroll
      for (int it = 0; it < 4; it++) {
        int r0 = wave * 32 + it * 8;
        lds16(&A16[(size_t)(m0 + r0 + (lane >> 3)) * K + k0 + ssw],
              &As[r0][0] + lane * 8);
        lds16(&BT[(size_t)(n0 + r0 + (lane >> 3)) * K + k0 + ssw],
              &Bs[r0][0] + lane * 8);
      }
    }
    __syncthreads();
#pragma unroll
    for (int ks = 0; ks < 64; ks += 32) {
      bf16x8 af[4], bfr[4];
#pragma unroll
      for (int i = 0; i < 4; i++)
        af[i] = *(const bf16x8*)&As[wr + i * 16 + l16][(((ks >> 3) + quad) ^ rsw) << 3];
#pragma unroll
      for (int j = 0; j < 4; j++)
        bfr[j] = *(const bf16x8*)&Bs[wc + j * 16 + l16][(((ks >> 3) + quad) ^ rsw) << 3];
#pragma unroll
      for (int i = 0; i < 4; i++)
#pragma unroll
        for (int j = 0; j < 4; j++)
          acc[i][j] = __builtin_amdgcn_mfma_f32_16x16x32_bf16(af[i], bfr[j], acc[i][j], 0, 0, 0);
    }
    __syncthreads();
  }

  // epilogue: C/D layout col=lane&15, row=quad*4+reg
#pragma unroll
  for (int i = 0; i < 4; i++) {
#pragma unroll
    for (int j = 0; j < 4; j++) {
      int col = n0 + wc + j * 16 + l16;
      float bv = bias ? bias[col] : 0.0f;
#pragma unroll
      for (int r = 0; r < 4; r++) {
        int row = m0 + wr + i * 16 + quad * 4 + r;
        float v = acc[i][j][r] + bv;
        if (Cf) Cf[(size_t)row * N + col] = v;
        else    Cb[(size_t)row * N + col] = f2bf(v);
      }
    }
  }
}

// ---------------------------------------------------------------------------
// Big-GEMM, 8-phase schedule (T2+T3+T4+T5 port of the m201 template):
// 256x256 tile, 512 threads (8 waves 2Mx4N, wave tile 128x64), BK=64,
// 2 dbuf x 2 half-slots per matrix (128 KiB LDS). Counted vmcnt(2) at
// phases 4/8 only. Used for the long-K qkv projection (K=1280, NT=20).
// ---------------------------------------------------------------------------
#define LDA_(d, ib) { _Pragma("unroll") for (int i = 0; i < 4; i++) \
  _Pragma("unroll") for (int ks = 0; ks < 2; ks++) \
    af[i*2+ks] = *(const bf16x8*)&As[d][wm][(ib+i)*16 + l16][((ks*4+quad) ^ rsw) << 3]; }

#define LDB_(d, dst, jp) { _Pragma("unroll") for (int j = 0; j < 2; j++) \
  _Pragma("unroll") for (int ks = 0; ks < 2; ks++) \
    dst[j*2+ks] = *(const bf16x8*)&Bs[d][bh][br + (jp*2+j)*16 + l16][((ks*4+quad) ^ rsw) << 3]; }

#define MM_(ib, jp, breg) { __builtin_amdgcn_s_setprio(1); \
  _Pragma("unroll") for (int i = 0; i < 4; i++) \
  _Pragma("unroll") for (int j = 0; j < 2; j++) \
  _Pragma("unroll") for (int ks = 0; ks < 2; ks++) \
    acc[ib+i][jp*2+j] = __builtin_amdgcn_mfma_f32_16x16x32_bf16( \
        af[i*2+ks], breg[j*2+ks], acc[ib+i][jp*2+j], 0, 0, 0); \
  __builtin_amdgcn_s_setprio(0); }

__global__ __launch_bounds__(512, 2)
void gemm_bt256(const u16* __restrict__ A16, const u16* __restrict__ BT,
                u16* __restrict__ Cb, int M, int N, int K)
{
  __shared__ __align__(16) u16 As[2][2][128][64];  // [dbuf][half][row][col]
  __shared__ __align__(16) u16 Bs[2][2][128][64];
  const int tid  = threadIdx.x;
  const int wave = tid >> 6, lane = tid & 63;
  const int quad = lane >> 4, l16 = lane & 15;
  const int wm = wave >> 2, wn = wave & 3;   // 2 x 4 wave grid
  const int bh = wn >> 1, br = (wn & 1) * 64;
  const int rsw = l16 & 7;

  const int nb = N >> 8, mb = M >> 8;
  int band, nblk;
  if ((mb & 7) == 0) {
    int xcd = blockIdx.x & 7, slot = blockIdx.x >> 3;
    band = xcd + 8 * (slot / nb);
    nblk = slot % nb;
  } else {
    band = blockIdx.x / nb;
    nblk = blockIdx.x % nb;
  }
  const int m0 = band * 256, n0 = nblk * 256;
  const int NT = K >> 6;                     // 64-wide K tiles (even, >=4)

  const int srow = tid >> 3;                 // 0..63
  const int scol = ((tid & 7) ^ (srow & 7)) << 3;  // pre-swizzled global col

  auto stageA = [&](int t, int h) {
    const int d = t & 1;
    const size_t g = (size_t)(m0 + h * 128 + srow) * K + (t << 6) + scol;
    lds16(&A16[g], &As[d][h][0][0] + tid * 8);
    lds16(&A16[g + (size_t)64 * K], &As[d][h][64][0] + tid * 8);
  };
  auto stageB = [&](int t, int h) {
    const int d = t & 1;
    const size_t g = (size_t)(n0 + h * 128 + srow) * K + (t << 6) + scol;
    lds16(&BT[g], &Bs[d][h][0][0] + tid * 8);
    lds16(&BT[g + (size_t)64 * K], &Bs[d][h][64][0] + tid * 8);
  };

  bf16x8 af[8], b0[4], b1[4];
  f32x4 acc[8][4];
#pragma unroll
  for (int i = 0; i < 8; i++)
#pragma unroll
    for (int j = 0; j < 4; j++) acc[i][j] = f32x4{0.f, 0.f, 0.f, 0.f};

  // prologue: tile0 complete + tile1 A-half0
  stageA(0, 0); stageA(0, 1); stageB(0, 0); stageB(0, 1); stageA(1, 0);
  VMC(2);
  BAR();

  const int nIter = NT >> 1;
  for (int it = 0; it < nIter; ++it) {
    const int t0 = it * 2, t1 = t0 + 1;
    const bool more  = (t0 + 2 < NT);
    const bool more1 = (t1 + 2 < NT);

    // ---- dbuf0 (tile t0) ----
    LDA_(0, 0); LDB_(0, b0, 0);
    stageA(t1, 1);
    BAR(); MM_(0, 0, b0); BAR();
    LDB_(0, b1, 1);
    stageB(t1, 0);
    BAR(); MM_(0, 1, b1); BAR();
    LDA_(0, 4);
    stageB(t1, 1);
    BAR(); MM_(4, 1, b1); BAR();
    if (more) stageA(t0 + 2, 0);
    BAR(); MM_(4, 0, b0);
    if (more) { VMC(2); } else { VMC(0); }
    BAR();

    // ---- dbuf1 (tile t1) ----
    LDA_(1, 0); LDB_(1, b0, 0);
    if (more) stageA(t0 + 2, 1);
    BAR(); MM_(0, 0, b0); BAR();
    LDB_(1, b1, 1);
    if (more) stageB(t0 + 2, 0);
    BAR(); MM_(0, 1, b1); BAR();
    LDA_(1, 4);
    if (more) stageB(t0 + 2, 1);
    BAR(); MM_(4, 1, b1); BAR();
    if (more1) stageA(t1 + 2, 0);
    BAR(); MM_(4, 0, b0);
    if (it + 1 < nIter) {
      if (more1) { VMC(2); } else { VMC(0); }
      BAR();
    }
  }

  // epilogue: C/D layout col=lane&15, row=quad*4+reg
#pragma unroll
  for (int i = 0; i < 8; i++) {
#pragma unroll
    for (int j = 0; j < 4; j++) {
      const int col = n0 + wn * 64 + j * 16 + l16;
#pragma unroll
      for (int r = 0; r < 4; r++) {
        const int row = m0 + wm * 128 + i * 16 + quad * 4 + r;
        Cb[(size_t)row * N + col] = f2bf(acc[i][j][r]);
      }
    }
  }
}

// ---------------------------------------------------------------------------
// One-shot V transpose with PV-fragment key permutation baked in:
// within each 32-key block, output slot s holds keys matching the lane-local
// layout of P after the S^T QK^T, so attention builds its PV A-fragment
// entirely in-register (no P LDS round-trip).
// ---------------------------------------------------------------------------
__global__ __launch_bounds__(256)
void vtrans(const u16* __restrict__ qkv, u16* __restrict__ vT)
{
  __shared__ u16 T[32][72];
  const int tid   = threadIdx.x;
  const int kt    = blockIdx.x;        // 0..15 : 64-token tile
  const int head  = blockIdx.y >> 2;   // 0..7
  const int chunk = blockIdx.y & 3;    // 0..3
  const int b     = blockIdx.z;        // 0..3
  const size_t rowbase = (size_t)b * 4096 + chunk * 1024 + kt * 64;

  const int tok = tid >> 2;            // 0..63
  const int d8  = (tid & 3) << 3;      // 0,8,16,24
  u16x8 vv = *(const u16x8*)&qkv[(rowbase + tok) * 768 + 512 + head * 32 + d8];
  const int rot = (tok + (d8 >> 3)) & 7;
#pragma unroll
  for (int jj = 0; jj < 8; jj++) {
    int j = (jj + rot) & 7;
    T[d8 + j][tok] = vv[j];
  }
  __syncthreads();
  const int d = tid >> 3;              // 0..31
  const int s = tid & 7;               // output slot-group (8 keys)
  const int base = ((s >> 2) << 5) + ((s & 3) << 2);   // b32*32 + quad*4
  u16x4 lo = *(const u16x4*)&T[d][base];        // keys quad*4 + 0..3
  u16x4 hi = *(const u16x4*)&T[d][base + 16];   // keys quad*4 + 16..19
  u16x8 o8;
  o8[0]=lo[0]; o8[1]=lo[1]; o8[2]=lo[2]; o8[3]=lo[3];
  o8[4]=hi[0]; o8[5]=hi[1]; o8[6]=hi[2]; o8[7]=hi[3];
  size_t obase = ((size_t)((b * 4 + chunk) * 8 + head)) * 32768
               + (size_t)d * 1024 + kt * 64 + s * 8;
  *(u16x8*)&vT[obase] = o8;
}

// ---------------------------------------------------------------------------
// Block-diagonal attention. Q pre-scaled by SCALE*log2e in the projection.
// K and V^T staged via global_load_lds DMA into a 4-buffer ring, 2 tiles
// ahead, counted vmcnt(2) per iteration. P never touches LDS (vtrans baked
// key-perm). Softmax denominator via ones-B MFMA: moves the 24 lsum adds
// per iter from the (bottleneck) VALU pipe to the matrix pipe AND lands the
// row-sum in the lane that needs it (no epilogue shuffle reduction).
// Denominator sums the SAME rounded-bf16 P the numerator uses (consistent).
// ---------------------------------------------------------------------------
__global__ __launch_bounds__(256)
void attn_kernel(const u16* __restrict__ qkv, const u16* __restrict__ vT,
                 u16* __restrict__ o)
{
  __shared__ __align__(16) u16 Ks[4][64][32];    // keys [key][d]
  __shared__ __align__(16) u16 VTs[4][32][64];   // V^T [d][key-slot] (swz)

  const int tid  = threadIdx.x;
  const int wave = tid >> 6, lane = tid & 63;
  const int quad = lane >> 4, l16 = lane & 15;
  const int qb    = blockIdx.x;        // 0..7
  const int head  = blockIdx.y >> 2;   // 0..7
  const int chunk = blockIdx.y & 3;    // 0..3
  const int b     = blockIdx.z;        // 0..3
  const size_t rowbase = (size_t)b * 4096 + chunk * 1024;
  const int tok0 = qb * 128 + wave * 32;

  const int kkey = tid >> 2;                     // 0..63
  const int kd8  = (tid & 3) << 3;               // 0,8,16,24
  const int vr   = tid >> 3;                     // d row 0..31
  const int vs   = tid & 7;                      // LDS slot'
  const int vsl  = (vs ^ (vr & 7)) << 3;         // content offset (XOR swz)
  const size_t vbase = ((size_t)((b * 4 + chunk) * 8 + head)) * 32768
                     + (size_t)vr * 1024 + vsl;

  auto stageKV = [&](int kb, int buf) {
    lds16(&qkv[(rowbase + kb * 64 + kkey) * 768 + 256 + head * 32 + kd8],
          &Ks[buf][0][0] + tid * 8);
    lds16(&vT[vbase + (size_t)kb * 64], &VTs[buf][0][0] + tid * 8);
  };

  stageKV(0, 0);

  bf16x8 qf[2];
#pragma unroll
  for (int qt = 0; qt < 2; qt++)
    qf[qt] = *(const bf16x8*)&qkv[(rowbase + tok0 + qt * 16 + l16) * 768 + head * 32 + quad * 8];

  stageKV(1, 1);

  // all-ones bf16 B-fragment for the denominator MFMA
  bf16x8 onesb;
  {
    union { u16x8 u; bf16x8 v; } c;
#pragma unroll
    for (int i = 0; i < 8; i++) c.u[i] = 0x3F80;
    onesb = c.v;
  }

  f32x4 Oacc[2][2], Osum[2];
#pragma unroll
  for (int qt = 0; qt < 2; qt++) {
    Osum[qt] = f32x4{0.f, 0.f, 0.f, 0.f};
#pragma unroll
    for (int nd = 0; nd < 2; nd++) Oacc[qt][nd] = f32x4{0.f, 0.f, 0.f, 0.f};
  }

  VMC(2);          // buf0 landed (stage(1) may stay in flight)
  BAR();

  for (int kb = 0; kb < 16; kb++) {
    const int cur = kb & 3;
    if (kb + 2 < 16) stageKV(kb + 2, (kb + 2) & 3);

    bf16x8 kf[4];
#pragma unroll
    for (int kt = 0; kt < 4; kt++)
      kf[kt] = *(const bf16x8*)&Ks[cur][kt * 16 + l16][quad * 8];

    f32x4 ST[4][2];
    __builtin_amdgcn_s_setprio(1);
#pragma unroll
    for (int kt = 0; kt < 4; kt++)
#pragma unroll
      for (int qt = 0; qt < 2; qt++)
        ST[kt][qt] = __builtin_amdgcn_mfma_f32_16x16x32_bf16(kf[kt], qf[qt], f32x4{0.f,0.f,0.f,0.f}, 0, 0, 0);
    __builtin_amdgcn_s_setprio(0);

    // softmax weights, packed lane-locally (no LDS round-trip, no lsum adds)
    u32 pw[2][4][2];
#pragma unroll
    for (int qt = 0; qt < 2; qt++)
#pragma unroll
      for (int kt = 0; kt < 4; kt++) {
        float p0 = fexp2(ST[kt][qt][0]);
        float p1 = fexp2(ST[kt][qt][1]);
        float p2 = fexp2(ST[kt][qt][2]);
        float p3 = fexp2(ST[kt][qt][3]);
        pw[qt][kt][0] = cvtpk(p0, p1);
        pw[qt][kt][1] = cvtpk(p2, p3);
      }

#pragma unroll
    for (int ks = 0; ks < 2; ks++) {
      bf16x8 vf[2];
#pragma unroll
      for (int nd = 0; nd < 2; nd++)
        vf[nd] = *(const bf16x8*)&VTs[cur][nd * 16 + l16][((ks * 4 + quad) ^ (l16 & 7)) << 3];
      __builtin_amdgcn_s_setprio(1);
#pragma unroll
      for (int qt = 0; qt < 2; qt++) {
        union { u32 w[4]; bf16x8 v; } pu;
        pu.w[0] = pw[qt][2 * ks][0];
        pu.w[1] = pw[qt][2 * ks][1];
        pu.w[2] = pw[qt][2 * ks + 1][0];
        pu.w[3] = pw[qt][2 * ks + 1][1];
#pragma unroll
        for (int nd = 0; nd < 2; nd++)
          Oacc[qt][nd] = __builtin_amdgcn_mfma_f32_16x16x32_bf16(pu.v, vf[nd], Oacc[qt][nd], 0, 0, 0);
        Osum[qt] = __builtin_amdgcn_mfma_f32_16x16x32_bf16(pu.v, onesb, Osum[qt], 0, 0, 0);
      }
      __builtin_amdgcn_s_setprio(0);
    }

    if (kb < 15) {
      if (kb + 2 < 16) { VMC(2); } else { VMC(0); }
      BAR();
    }
  }

  // epilogue: Osum[qt][r] is the denominator for this lane's own row
  // (C layout: row = quad*4+r, every col identical) -> no shuffles.
#pragma unroll
  for (int qt = 0; qt < 2; qt++)
#pragma unroll
    for (int r = 0; r < 4; r++) {
      float inv = 1.0f / Osum[qt][r];
      size_t row = rowbase + tok0 + qt * 16 + quad * 4 + r;
#pragma unroll
      for (int nd = 0; nd < 2; nd++) {
        int col = head * 32 + nd * 16 + l16;
        o[row * 256 + col] = f2bf(Oacc[qt][nd][r] * inv);
      }
    }
}

// ---------------------------------------------------------------------------
extern "C" void kernel_launch(void* const* d_in, const int* in_sizes, int n_in,
                              void* d_out, int out_size, void* d_ws, size_t ws_size,
                              hipStream_t stream)
{
  const float* x    = (const float*)d_in[0];
  const float* Wd   = (const float*)d_in[1];
  const float* Wqkv = (const float*)d_in[2];
  const float* Wup  = (const float*)d_in[3];
  const float* bup  = (const float*)d_in[4];
  float* out = (float*)d_out;

  const int M = 4 * 4096;  // 16384 tokens

  // workspace (u16 elems): WdC | WqkvT | WupT | WpT | qkv | ob | xb(optional)
  u16* WdC   = (u16*)d_ws;              // Wd cast      [1280][256]
  u16* WqkvT = WdC   + 1280 * 256;      // Wqkv^T       [768][256] (Q rows *CEXP)
  u16* WupT  = WqkvT + 768 * 256;       // Wup^T        [1280][256]
  u16* WpT   = WupT  + 1280 * 256;      // (Wd@Wqkv)^T  [768][1280]
  u16* qkv   = WpT   + 768 * 1280;      // [16384][768]
  u16* ob    = qkv   + (size_t)M * 768; // [16384][256]
  u16* xb    = ob    + (size_t)M * 256; // [16384][1280] bf16 cast of x
  // vT aliases xb: xb is dead after the qkv GEMM; vtrans runs after it.
  u16* vT    = xb;                      // [128][32][1024] V transposed (perm'd)

  const size_t need = ((size_t)(1280*256 + 768*256 + 1280*256 + 768*1280)
                       + (size_t)M * (768 + 256 + 1280)) * sizeof(u16);
  const bool use_xb = ws_size >= need;  // ws_size constant across calls

  const int n8 = use_xb ? (M * 1280 / 8) : 0;
  prep_all<<<(PREP_W + n8 + 255) / 256, 256, 0, stream>>>(
      Wd, Wqkv, Wup, x, WdC, WqkvT, WupT, xb, n8);

  // W'^T[n][k] = sum_c WqkvT[n][c] * Wd[k][c]  -> [768][1280] bf16
  gemm_bt<0><<<dim3((1280 / 128) * (768 / 128)), 256, 0, stream>>>(
      (const void*)WqkvT, WdC, WpT, nullptr, nullptr, 768, 1280, 256);

  if (use_xb) {
    gemm_bt256<<<dim3((768 / 256) * (M / 256)), 512, 0, stream>>>(
        xb, WpT, qkv, M, 768, 1280);
  } else {
    gemm_bt<1><<<dim3((768 / 128) * (M / 128)), 256, 0, stream>>>(
        (const void*)x, WpT, qkv, nullptr, nullptr, M, 768, 1280);
  }

  // one-shot V transpose (writes over the dead xb region)
  vtrans<<<dim3(16, 32, 4), 256, 0, stream>>>(qkv, vT);

  // block-diagonal attention
  attn_kernel<<<dim3(8, 32, 4), 256, 0, stream>>>(qkv, vT, ob);

  // out = o @ Wup + bup (f32 out) — 128^2 swizzled path (K=256 is too short
  // for the 8-phase 256^2 pipeline: NT=4 never reaches steady state)
  gemm_bt<0><<<dim3((1280 / 128) * (M / 128)), 256, 0, stream>>>(
      (const void*)ob, WupT, nullptr, out, bup, M, 1280, 256);
}

// Round 6
// 259.754 us; speedup vs baseline: 1.0691x; 1.0544x over previous
//
#include <hip/hip_runtime.h>

typedef unsigned short u16;
typedef unsigned int u32;
typedef u16 u16x4 __attribute__((ext_vector_type(4)));
typedef u16 u16x8 __attribute__((ext_vector_type(8)));
typedef __bf16 bf16x8 __attribute__((ext_vector_type(8)));
typedef float f32x4 __attribute__((ext_vector_type(4)));

__device__ __forceinline__ u16 f2bf(float f) {
  union { float f; unsigned u; } c; c.f = f;
  unsigned u = c.u;
  return (u16)((u + 0x7fff + ((u >> 16) & 1)) >> 16);
}

// fast exp2: scores are bounded (|S| ~ 4), raw v_exp_f32 is safe (1 ULP)
__device__ __forceinline__ float fexp2(float x) {
  float r; asm("v_exp_f32 %0, %1" : "=v"(r) : "v"(x)); return r;
}

// pack two f32 -> bf16x2 in one instruction (T12 recipe; no builtin on gfx950)
__device__ __forceinline__ u32 cvtpk(float lo, float hi) {
  u32 r;
  asm("v_cvt_pk_bf16_f32 %0, %1, %2" : "=v"(r) : "v"(lo), "v"(hi));
  return r;
}

// async global->LDS, 16B per lane. LDS dest must be wave-uniform base + lane*16.
__device__ __forceinline__ void lds16(const u16* g, u16* l) {
  __builtin_amdgcn_global_load_lds(
      (const __attribute__((address_space(1))) unsigned int*)g,
      (__attribute__((address_space(3))) unsigned int*)l, 16, 0, 0);
}

// SCALE = (1280//8)^-0.5, folded with log2(e); baked into Q-projection weights
#define CEXP (0.07905694150420949f * 1.4426950408889634f)

#define BAR()  do { asm volatile("" ::: "memory"); \
                    __builtin_amdgcn_s_barrier(); \
                    asm volatile("" ::: "memory"); } while (0)
#define VMC(n) asm volatile("s_waitcnt vmcnt(" #n ")" ::: "memory")

// ---------------------------------------------------------------------------
// weight prep only: Wd cast | Wqkv^T (+CEXP on Q rows) | Wup^T
// (x-cast moved into wpt_xcast so it overlaps the WpT GEMM)
// ---------------------------------------------------------------------------
#define PREP_W (1280 * 256 + 768 * 256 + 1280 * 256)   // 851968 weight elems

__global__ __launch_bounds__(256)
void prep_w(const float* __restrict__ Wd, const float* __restrict__ Wqkv,
            const float* __restrict__ Wup,
            u16* __restrict__ WdC, u16* __restrict__ WqkvT,
            u16* __restrict__ WupT) {
  int id = blockIdx.x * 256 + threadIdx.x;
  if (id < 1280 * 256) {                      // straight cast of Wd
    WdC[id] = f2bf(Wd[id]);
    return;
  }
  id -= 1280 * 256;
  if (id < 768 * 256) {                       // Wqkv^T, scale Q rows by CEXP
    int n = id >> 8, c = id & 255;
    float v = Wqkv[(size_t)c * 768 + n];
    if (n < 256) v *= CEXP;
    WqkvT[id] = f2bf(v);
    return;
  }
  id -= 768 * 256;
  if (id < 1280 * 256) {                      // Wup^T
    int n = id >> 8, c = id & 255;
    WupT[id] = f2bf(Wup[(size_t)c * 1280 + n]);
  }
}

// ---------------------------------------------------------------------------
// Fused: WpT GEMM (60 blocks, latency-bound) + x->bf16 cast (memory-bound).
// No data dependency between the two; block-range partition lets the cast
// waves fill the GEMM's latency bubbles instead of running serially.
// GEMM: WpT[768][1280] = WqkvT[768][256] * WdC[1280][256]^T  (m97+swizzle)
// ---------------------------------------------------------------------------
__global__ __launch_bounds__(256)
void wpt_xcast(const u16* __restrict__ WqkvT, const u16* __restrict__ WdC,
               u16* __restrict__ WpT,
               const float* __restrict__ X, u16* __restrict__ Xb, int n8)
{
  __shared__ u16 As[128][64];
  __shared__ u16 Bs[128][64];

  if (blockIdx.x >= 60) {                     // ---- x -> bf16 cast ----
    int id = (blockIdx.x - 60) * 256 + threadIdx.x;
    if (id < n8) {
      const float4* src = (const float4*)(X + (size_t)id * 8);
      float4 lo = src[0], hi = src[1];
      u16x8 v;
      v[0]=f2bf(lo.x); v[1]=f2bf(lo.y); v[2]=f2bf(lo.z); v[3]=f2bf(lo.w);
      v[4]=f2bf(hi.x); v[5]=f2bf(hi.y); v[6]=f2bf(hi.z); v[7]=f2bf(hi.w);
      *(u16x8*)(Xb + (size_t)id * 8) = v;
    }
    return;
  }

  // ---- WpT GEMM, M=768 N=1280 K=256 ----
  const int tid  = threadIdx.x;
  const int wave = tid >> 6, lane = tid & 63;
  const int quad = lane >> 4, l16 = lane & 15;
  const int rsw  = l16 & 7;
  const int ssw  = ((lane & 7) ^ (lane >> 3)) << 3;
  const int band = blockIdx.x / 10, nblk = blockIdx.x % 10;
  const int m0 = band * 128, n0 = nblk * 128;
  const int wr = (wave >> 1) * 64, wc = (wave & 1) * 64;
  const int K = 256, N = 1280;

  f32x4 acc[4][4];
#pragma unroll
  for (int i = 0; i < 4; i++)
#pragma unroll
    for (int j = 0; j < 4; j++) acc[i][j] = f32x4{0.f, 0.f, 0.f, 0.f};

  for (int k0 = 0; k0 < K; k0 += 64) {
#pragma unroll
    for (int it = 0; it < 4; it++) {
      int r0 = wave * 32 + it * 8;
      lds16(&WqkvT[(size_t)(m0 + r0 + (lane >> 3)) * K + k0 + ssw],
            &As[r0][0] + lane * 8);
      lds16(&WdC[(size_t)(n0 + r0 + (lane >> 3)) * K + k0 + ssw],
            &Bs[r0][0] + lane * 8);
    }
    __syncthreads();
#pragma unroll
    for (int ks = 0; ks < 64; ks += 32) {
      bf16x8 af[4], bfr[4];
#pragma unroll
      for (int i = 0; i < 4; i++)
        af[i] = *(const bf16x8*)&As[wr + i * 16 + l16][(((ks >> 3) + quad) ^ rsw) << 3];
#pragma unroll
      for (int j = 0; j < 4; j++)
        bfr[j] = *(const bf16x8*)&Bs[wc + j * 16 + l16][(((ks >> 3) + quad) ^ rsw) << 3];
#pragma unroll
      for (int i = 0; i < 4; i++)
#pragma unroll
        for (int j = 0; j < 4; j++)
          acc[i][j] = __builtin_amdgcn_mfma_f32_16x16x32_bf16(af[i], bfr[j], acc[i][j], 0, 0, 0);
    }
    __syncthreads();
  }

#pragma unroll
  for (int i = 0; i < 4; i++)
#pragma unroll
    for (int j = 0; j < 4; j++) {
      int col = n0 + wc + j * 16 + l16;
#pragma unroll
      for (int r = 0; r < 4; r++) {
        int row = m0 + wr + i * 16 + quad * 4 + r;
        WpT[(size_t)row * N + col] = f2bf(acc[i][j][r]);
      }
    }
}

// ---------------------------------------------------------------------------
// GEMM: C[M,N] = A[M,K] * BT[N,K]^T (+bias). m97 structure + content-XOR
// LDS swizzle. 128x128 tile, 4 waves of 64x64, BK=64. Used for the final
// f32-out projection and the AF32 fallback.
// ---------------------------------------------------------------------------
template <int AF32>
__global__ __launch_bounds__(256)
void gemm_bt(const void* __restrict__ Av,
             const u16* __restrict__ BT,
             u16* __restrict__ Cb, float* __restrict__ Cf,
             const float* __restrict__ bias,
             int M, int N, int K)
{
  __shared__ u16 As[128][64];
  __shared__ u16 Bs[128][64];
  const int tid  = threadIdx.x;
  const int wave = tid >> 6, lane = tid & 63;
  const int quad = lane >> 4, l16 = lane & 15;
  const int rsw  = l16 & 7;                 // read-side row XOR
  const int ssw  = ((lane & 7) ^ (lane >> 3)) << 3;  // staging col (pre-swz)

  const int nb = N >> 7, mb = M >> 7;
  int band, nblk;
  if ((mb & 7) == 0) {
    int xcd = blockIdx.x & 7, slot = blockIdx.x >> 3;
    band = xcd + 8 * (slot / nb);
    nblk = slot % nb;
  } else {
    band = blockIdx.x / nb;
    nblk = blockIdx.x % nb;
  }
  const int m0 = band * 128, n0 = nblk * 128;
  const int wr = (wave >> 1) * 64, wc = (wave & 1) * 64;
  const u16*   A16 = (const u16*)Av;
  const float* A32 = (const float*)Av;

  f32x4 acc[4][4];
#pragma unroll
  for (int i = 0; i < 4; i++)
#pragma unroll
    for (int j = 0; j < 4; j++) acc[i][j] = f32x4{0.f, 0.f, 0.f, 0.f};

  for (int k0 = 0; k0 < K; k0 += 64) {
    if constexpr (AF32) {
#pragma unroll
      for (int it = 0; it < 4; it++) {
        int idx = tid + it * 256;
        int r = idx >> 3;
        const float* src = &A32[(size_t)(m0 + r) * K + k0 + ((idx & 7) << 3)];
        float4 lo = *(const float4*)src;
        float4 hi = *(const float4*)(src + 4);
        u16x8 v;
        v[0]=f2bf(lo.x); v[1]=f2bf(lo.y); v[2]=f2bf(lo.z); v[3]=f2bf(lo.w);
        v[4]=f2bf(hi.x); v[5]=f2bf(hi.y); v[6]=f2bf(hi.z); v[7]=f2bf(hi.w);
        *(u16x8*)&As[r][((idx & 7) ^ (r & 7)) << 3] = v;
      }
#pragma unroll
      for (int it = 0; it < 4; it++) {
        int r0 = wave * 32 + it * 8;
        lds16(&BT[(size_t)(n0 + r0 + (lane >> 3)) * K + k0 + ssw],
              &Bs[r0][0] + lane * 8);
      }
    } else {
#pragma unroll
      for (int it = 0; it < 4; it++) {
        int r0 = wave * 32 + it * 8;
        lds16(&A16[(size_t)(m0 + r0 + (lane >> 3)) * K + k0 + ssw],
              &As[r0][0] + lane * 8);
        lds16(&BT[(size_t)(n0 + r0 + (lane >> 3)) * K + k0 + ssw],
              &Bs[r0][0] + lane * 8);
      }
    }
    __syncthreads();
#pragma unroll
    for (int ks = 0; ks < 64; ks += 32) {
      bf16x8 af[4], bfr[4];
#pragma unroll
      for (int i = 0; i < 4; i++)
        af[i] = *(const bf16x8*)&As[wr + i * 16 + l16][(((ks >> 3) + quad) ^ rsw) << 3];
#pragma unroll
      for (int j = 0; j < 4; j++)
        bfr[j] = *(const bf16x8*)&Bs[wc + j * 16 + l16][(((ks >> 3) + quad) ^ rsw) << 3];
#pragma unroll
      for (int i = 0; i < 4; i++)
#pragma unroll
        for (int j = 0; j < 4; j++)
          acc[i][j] = __builtin_amdgcn_mfma_f32_16x16x32_bf16(af[i], bfr[j], acc[i][j], 0, 0, 0);
    }
    __syncthreads();
  }

  // epilogue: C/D layout col=lane&15, row=quad*4+reg
#pragma unroll
  for (int i = 0; i < 4; i++) {
#pragma unroll
    for (int j = 0; j < 4; j++) {
      int col = n0 + wc + j * 16 + l16;
      float bv = bias ? bias[col] : 0.0f;
#pragma unroll
      for (int r = 0; r < 4; r++) {
        int row = m0 + wr + i * 16 + quad * 4 + r;
        float v = acc[i][j][r] + bv;
        if (Cf) Cf[(size_t)row * N + col] = v;
        else    Cb[(size_t)row * N + col] = f2bf(v);
      }
    }
  }
}

// ---------------------------------------------------------------------------
// Big-GEMM, 8-phase schedule (T2+T3+T4+T5 port of the m201 template):
// 256x256 tile, 512 threads (8 waves 2Mx4N, wave tile 128x64), BK=64,
// 2 dbuf x 2 half-slots per matrix (128 KiB LDS). Counted vmcnt(2) at
// phases 4/8 only. Used for the long-K qkv projection (K=1280, NT=20).
// ---------------------------------------------------------------------------
#define LDA_(d, ib) { _Pragma("unroll") for (int i = 0; i < 4; i++) \
  _Pragma("unroll") for (int ks = 0; ks < 2; ks++) \
    af[i*2+ks] = *(const bf16x8*)&As[d][wm][(ib+i)*16 + l16][((ks*4+quad) ^ rsw) << 3]; }

#define LDB_(d, dst, jp) { _Pragma("unroll") for (int j = 0; j < 2; j++) \
  _Pragma("unroll") for (int ks = 0; ks < 2; ks++) \
    dst[j*2+ks] = *(const bf16x8*)&Bs[d][bh][br + (jp*2+j)*16 + l16][((ks*4+quad) ^ rsw) << 3]; }

#define MM_(ib, jp, breg) { __builtin_amdgcn_s_setprio(1); \
  _Pragma("unroll") for (int i = 0; i < 4; i++) \
  _Pragma("unroll") for (int j = 0; j < 2; j++) \
  _Pragma("unroll") for (int ks = 0; ks < 2; ks++) \
    acc[ib+i][jp*2+j] = __builtin_amdgcn_mfma_f32_16x16x32_bf16( \
        af[i*2+ks], breg[j*2+ks], acc[ib+i][jp*2+j], 0, 0, 0); \
  __builtin_amdgcn_s_setprio(0); }

__global__ __launch_bounds__(512, 2)
void gemm_bt256(const u16* __restrict__ A16, const u16* __restrict__ BT,
                u16* __restrict__ Cb, int M, int N, int K)
{
  __shared__ __align__(16) u16 As[2][2][128][64];  // [dbuf][half][row][col]
  __shared__ __align__(16) u16 Bs[2][2][128][64];
  const int tid  = threadIdx.x;
  const int wave = tid >> 6, lane = tid & 63;
  const int quad = lane >> 4, l16 = lane & 15;
  const int wm = wave >> 2, wn = wave & 3;   // 2 x 4 wave grid
  const int bh = wn >> 1, br = (wn & 1) * 64;
  const int rsw = l16 & 7;

  const int nb = N >> 8, mb = M >> 8;
  int band, nblk;
  if ((mb & 7) == 0) {
    int xcd = blockIdx.x & 7, slot = blockIdx.x >> 3;
    band = xcd + 8 * (slot / nb);
    nblk = slot % nb;
  } else {
    band = blockIdx.x / nb;
    nblk = blockIdx.x % nb;
  }
  const int m0 = band * 256, n0 = nblk * 256;
  const int NT = K >> 6;                     // 64-wide K tiles (even, >=4)

  const int srow = tid >> 3;                 // 0..63
  const int scol = ((tid & 7) ^ (srow & 7)) << 3;  // pre-swizzled global col

  auto stageA = [&](int t, int h) {
    const int d = t & 1;
    const size_t g = (size_t)(m0 + h * 128 + srow) * K + (t << 6) + scol;
    lds16(&A16[g], &As[d][h][0][0] + tid * 8);
    lds16(&A16[g + (size_t)64 * K], &As[d][h][64][0] + tid * 8);
  };
  auto stageB = [&](int t, int h) {
    const int d = t & 1;
    const size_t g = (size_t)(n0 + h * 128 + srow) * K + (t << 6) + scol;
    lds16(&BT[g], &Bs[d][h][0][0] + tid * 8);
    lds16(&BT[g + (size_t)64 * K], &Bs[d][h][64][0] + tid * 8);
  };

  bf16x8 af[8], b0[4], b1[4];
  f32x4 acc[8][4];
#pragma unroll
  for (int i = 0; i < 8; i++)
#pragma unroll
    for (int j = 0; j < 4; j++) acc[i][j] = f32x4{0.f, 0.f, 0.f, 0.f};

  // prologue: tile0 complete + tile1 A-half0
  stageA(0, 0); stageA(0, 1); stageB(0, 0); stageB(0, 1); stageA(1, 0);
  VMC(2);
  BAR();

  const int nIter = NT >> 1;
  for (int it = 0; it < nIter; ++it) {
    const int t0 = it * 2, t1 = t0 + 1;
    const bool more  = (t0 + 2 < NT);
    const bool more1 = (t1 + 2 < NT);

    // ---- dbuf0 (tile t0) ----
    LDA_(0, 0); LDB_(0, b0, 0);
    stageA(t1, 1);
    BAR(); MM_(0, 0, b0); BAR();
    LDB_(0, b1, 1);
    stageB(t1, 0);
    BAR(); MM_(0, 1, b1); BAR();
    LDA_(0, 4);
    stageB(t1, 1);
    BAR(); MM_(4, 1, b1); BAR();
    if (more) stageA(t0 + 2, 0);
    BAR(); MM_(4, 0, b0);
    if (more) { VMC(2); } else { VMC(0); }
    BAR();

    // ---- dbuf1 (tile t1) ----
    LDA_(1, 0); LDB_(1, b0, 0);
    if (more) stageA(t0 + 2, 1);
    BAR(); MM_(0, 0, b0); BAR();
    LDB_(1, b1, 1);
    if (more) stageB(t0 + 2, 0);
    BAR(); MM_(0, 1, b1); BAR();
    LDA_(1, 4);
    if (more) stageB(t0 + 2, 1);
    BAR(); MM_(4, 1, b1); BAR();
    if (more1) stageA(t1 + 2, 0);
    BAR(); MM_(4, 0, b0);
    if (it + 1 < nIter) {
      if (more1) { VMC(2); } else { VMC(0); }
      BAR();
    }
  }

  // epilogue: C/D layout col=lane&15, row=quad*4+reg
#pragma unroll
  for (int i = 0; i < 8; i++) {
#pragma unroll
    for (int j = 0; j < 4; j++) {
      const int col = n0 + wn * 64 + j * 16 + l16;
#pragma unroll
      for (int r = 0; r < 4; r++) {
        const int row = m0 + wm * 128 + i * 16 + quad * 4 + r;
        Cb[(size_t)row * N + col] = f2bf(acc[i][j][r]);
      }
    }
  }
}

// ---------------------------------------------------------------------------
// One-shot V transpose with PV-fragment key permutation baked in:
// within each 32-key block, output slot s holds keys matching the lane-local
// layout of P after the S^T QK^T, so attention builds its PV A-fragment
// entirely in-register (no P LDS round-trip).
// ---------------------------------------------------------------------------
__global__ __launch_bounds__(256)
void vtrans(const u16* __restrict__ qkv, u16* __restrict__ vT)
{
  __shared__ u16 T[32][72];
  const int tid   = threadIdx.x;
  const int kt    = blockIdx.x;        // 0..15 : 64-token tile
  const int head  = blockIdx.y >> 2;   // 0..7
  const int chunk = blockIdx.y & 3;    // 0..3
  const int b     = blockIdx.z;        // 0..3
  const size_t rowbase = (size_t)b * 4096 + chunk * 1024 + kt * 64;

  const int tok = tid >> 2;            // 0..63
  const int d8  = (tid & 3) << 3;      // 0,8,16,24
  u16x8 vv = *(const u16x8*)&qkv[(rowbase + tok) * 768 + 512 + head * 32 + d8];
  const int rot = (tok + (d8 >> 3)) & 7;
#pragma unroll
  for (int jj = 0; jj < 8; jj++) {
    int j = (jj + rot) & 7;
    T[d8 + j][tok] = vv[j];
  }
  __syncthreads();
  const int d = tid >> 3;              // 0..31
  const int s = tid & 7;               // output slot-group (8 keys)
  const int base = ((s >> 2) << 5) + ((s & 3) << 2);   // b32*32 + quad*4
  u16x4 lo = *(const u16x4*)&T[d][base];        // keys quad*4 + 0..3
  u16x4 hi = *(const u16x4*)&T[d][base + 16];   // keys quad*4 + 16..19
  u16x8 o8;
  o8[0]=lo[0]; o8[1]=lo[1]; o8[2]=lo[2]; o8[3]=lo[3];
  o8[4]=hi[0]; o8[5]=hi[1]; o8[6]=hi[2]; o8[7]=hi[3];
  size_t obase = ((size_t)((b * 4 + chunk) * 8 + head)) * 32768
               + (size_t)d * 1024 + kt * 64 + s * 8;
  *(u16x8*)&vT[obase] = o8;
}

// ---------------------------------------------------------------------------
// Block-diagonal attention. Q pre-scaled by SCALE*log2e in the projection.
// K and V^T staged via global_load_lds DMA into a 4-buffer ring, 2 tiles
// ahead, counted vmcnt(2) per iteration. P never touches LDS. Softmax
// denominator via ones-B MFMA. Grid: 1-D 1024 with gid = qb*128 + g so the
// 8 qb-blocks sharing one (b,head,chunk)'s K/V land on ONE XCD (gid mod 8 =
// g mod 8): K/V (128 KB/group, 2 MB/XCD) becomes L2-resident instead of 8
// XCDs each pulling it from L3.
// ---------------------------------------------------------------------------
__global__ __launch_bounds__(256)
void attn_kernel(const u16* __restrict__ qkv, const u16* __restrict__ vT,
                 u16* __restrict__ o)
{
  __shared__ __align__(16) u16 Ks[4][64][32];    // keys [key][d]
  __shared__ __align__(16) u16 VTs[4][32][64];   // V^T [d][key-slot] (swz)

  const int tid  = threadIdx.x;
  const int wave = tid >> 6, lane = tid & 63;
  const int quad = lane >> 4, l16 = lane & 15;
  const int gid   = blockIdx.x;        // 0..1023
  const int qb    = gid >> 7;          // 0..7
  const int g     = gid & 127;         // group: shares K/V, pinned to XCD g&7
  const int head  = g >> 4;            // 0..7
  const int chunk = (g >> 2) & 3;      // 0..3
  const int b     = g & 3;             // 0..3
  const size_t rowbase = (size_t)b * 4096 + chunk * 1024;
  const int tok0 = qb * 128 + wave * 32;

  const int kkey = tid >> 2;                     // 0..63
  const int kd8  = (tid & 3) << 3;               // 0,8,16,24
  const int vr   = tid >> 3;                     // d row 0..31
  const int vs   = tid & 7;                      // LDS slot'
  const int vsl  = (vs ^ (vr & 7)) << 3;         // content offset (XOR swz)
  const size_t vbase = ((size_t)((b * 4 + chunk) * 8 + head)) * 32768
                     + (size_t)vr * 1024 + vsl;

  auto stageKV = [&](int kb, int buf) {
    lds16(&qkv[(rowbase + kb * 64 + kkey) * 768 + 256 + head * 32 + kd8],
          &Ks[buf][0][0] + tid * 8);
    lds16(&vT[vbase + (size_t)kb * 64], &VTs[buf][0][0] + tid * 8);
  };

  stageKV(0, 0);

  bf16x8 qf[2];
#pragma unroll
  for (int qt = 0; qt < 2; qt++)
    qf[qt] = *(const bf16x8*)&qkv[(rowbase + tok0 + qt * 16 + l16) * 768 + head * 32 + quad * 8];

  stageKV(1, 1);

  // all-ones bf16 B-fragment for the denominator MFMA
  bf16x8 onesb;
  {
    union { u16x8 u; bf16x8 v; } c;
#pragma unroll
    for (int i = 0; i < 8; i++) c.u[i] = 0x3F80;
    onesb = c.v;
  }

  f32x4 Oacc[2][2], Osum[2];
#pragma unroll
  for (int qt = 0; qt < 2; qt++) {
    Osum[qt] = f32x4{0.f, 0.f, 0.f, 0.f};
#pragma unroll
    for (int nd = 0; nd < 2; nd++) Oacc[qt][nd] = f32x4{0.f, 0.f, 0.f, 0.f};
  }

  VMC(2);          // buf0 landed (stage(1) may stay in flight)
  BAR();

  for (int kb = 0; kb < 16; kb++) {
    const int cur = kb & 3;
    if (kb + 2 < 16) stageKV(kb + 2, (kb + 2) & 3);

    bf16x8 kf[4];
#pragma unroll
    for (int kt = 0; kt < 4; kt++)
      kf[kt] = *(const bf16x8*)&Ks[cur][kt * 16 + l16][quad * 8];

    f32x4 ST[4][2];
    __builtin_amdgcn_s_setprio(1);
#pragma unroll
    for (int kt = 0; kt < 4; kt++)
#pragma unroll
      for (int qt = 0; qt < 2; qt++)
        ST[kt][qt] = __builtin_amdgcn_mfma_f32_16x16x32_bf16(kf[kt], qf[qt], f32x4{0.f,0.f,0.f,0.f}, 0, 0, 0);
    __builtin_amdgcn_s_setprio(0);

    // softmax weights, packed lane-locally (no LDS round-trip, no lsum adds)
    u32 pw[2][4][2];
#pragma unroll
    for (int qt = 0; qt < 2; qt++)
#pragma unroll
      for (int kt = 0; kt < 4; kt++) {
        float p0 = fexp2(ST[kt][qt][0]);
        float p1 = fexp2(ST[kt][qt][1]);
        float p2 = fexp2(ST[kt][qt][2]);
        float p3 = fexp2(ST[kt][qt][3]);
        pw[qt][kt][0] = cvtpk(p0, p1);
        pw[qt][kt][1] = cvtpk(p2, p3);
      }

#pragma unroll
    for (int ks = 0; ks < 2; ks++) {
      bf16x8 vf[2];
#pragma unroll
      for (int nd = 0; nd < 2; nd++)
        vf[nd] = *(const bf16x8*)&VTs[cur][nd * 16 + l16][((ks * 4 + quad) ^ (l16 & 7)) << 3];
      __builtin_amdgcn_s_setprio(1);
#pragma unroll
      for (int qt = 0; qt < 2; qt++) {
        union { u32 w[4]; bf16x8 v; } pu;
        pu.w[0] = pw[qt][2 * ks][0];
        pu.w[1] = pw[qt][2 * ks][1];
        pu.w[2] = pw[qt][2 * ks + 1][0];
        pu.w[3] = pw[qt][2 * ks + 1][1];
#pragma unroll
        for (int nd = 0; nd < 2; nd++)
          Oacc[qt][nd] = __builtin_amdgcn_mfma_f32_16x16x32_bf16(pu.v, vf[nd], Oacc[qt][nd], 0, 0, 0);
        Osum[qt] = __builtin_amdgcn_mfma_f32_16x16x32_bf16(pu.v, onesb, Osum[qt], 0, 0, 0);
      }
      __builtin_amdgcn_s_setprio(0);
    }

    if (kb < 15) {
      if (kb + 2 < 16) { VMC(2); } else { VMC(0); }
      BAR();
    }
  }

  // epilogue: Osum[qt][r] is the denominator for this lane's own row
  // (C layout: row = quad*4+r, every col identical) -> no shuffles.
#pragma unroll
  for (int qt = 0; qt < 2; qt++)
#pragma unroll
    for (int r = 0; r < 4; r++) {
      float inv = 1.0f / Osum[qt][r];
      size_t row = rowbase + tok0 + qt * 16 + quad * 4 + r;
#pragma unroll
      for (int nd = 0; nd < 2; nd++) {
        int col = head * 32 + nd * 16 + l16;
        o[row * 256 + col] = f2bf(Oacc[qt][nd][r] * inv);
      }
    }
}

// ---------------------------------------------------------------------------
extern "C" void kernel_launch(void* const* d_in, const int* in_sizes, int n_in,
                              void* d_out, int out_size, void* d_ws, size_t ws_size,
                              hipStream_t stream)
{
  const float* x    = (const float*)d_in[0];
  const float* Wd   = (const float*)d_in[1];
  const float* Wqkv = (const float*)d_in[2];
  const float* Wup  = (const float*)d_in[3];
  const float* bup  = (const float*)d_in[4];
  float* out = (float*)d_out;

  const int M = 4 * 4096;  // 16384 tokens

  // workspace (u16 elems): WdC | WqkvT | WupT | WpT | qkv | ob | xb(optional)
  u16* WdC   = (u16*)d_ws;              // Wd cast      [1280][256]
  u16* WqkvT = WdC   + 1280 * 256;      // Wqkv^T       [768][256] (Q rows *CEXP)
  u16* WupT  = WqkvT + 768 * 256;       // Wup^T        [1280][256]
  u16* WpT   = WupT  + 1280 * 256;      // (Wd@Wqkv)^T  [768][1280]
  u16* qkv   = WpT   + 768 * 1280;      // [16384][768]
  u16* ob    = qkv   + (size_t)M * 768; // [16384][256]
  u16* xb    = ob    + (size_t)M * 256; // [16384][1280] bf16 cast of x
  // vT aliases xb: xb is dead after the qkv GEMM; vtrans runs after it.
  u16* vT    = xb;                      // [128][32][1024] V transposed (perm'd)

  const size_t need = ((size_t)(1280*256 + 768*256 + 1280*256 + 768*1280)
                       + (size_t)M * (768 + 256 + 1280)) * sizeof(u16);
  const bool use_xb = ws_size >= need;  // ws_size constant across calls

  // weight prep (small, fast)
  prep_w<<<(PREP_W + 255) / 256, 256, 0, stream>>>(
      Wd, Wqkv, Wup, WdC, WqkvT, WupT);

  // fused: WpT GEMM (60 blocks) overlapped with x->bf16 cast
  const int n8 = use_xb ? (M * 1280 / 8) : 0;
  wpt_xcast<<<60 + (n8 + 255) / 256, 256, 0, stream>>>(
      WqkvT, WdC, WpT, x, xb, n8);

  if (use_xb) {
    gemm_bt256<<<dim3((768 / 256) * (M / 256)), 512, 0, stream>>>(
        xb, WpT, qkv, M, 768, 1280);
  } else {
    gemm_bt<1><<<dim3((768 / 128) * (M / 128)), 256, 0, stream>>>(
        (const void*)x, WpT, qkv, nullptr, nullptr, M, 768, 1280);
  }

  // one-shot V transpose (writes over the dead xb region)
  vtrans<<<dim3(16, 32, 4), 256, 0, stream>>>(qkv, vT);

  // block-diagonal attention (XCD-grouped 1-D grid)
  attn_kernel<<<dim3(1024), 256, 0, stream>>>(qkv, vT, ob);

  // out = o @ Wup + bup (f32 out) — 128^2 swizzled path (K=256 is too short
  // for the 8-phase 256^2 pipeline: NT=4 never reaches steady state)
  gemm_bt<0><<<dim3((1280 / 128) * (M / 128)), 256, 0, stream>>>(
      (const void*)ob, WupT, nullptr, out, bup, M, 1280, 256);
}

// Round 8
// 249.782 us; speedup vs baseline: 1.1118x; 1.0399x over previous
//
#include <hip/hip_runtime.h>

typedef unsigned short u16;
typedef unsigned int u32;
typedef u16 u16x4 __attribute__((ext_vector_type(4)));
typedef u16 u16x8 __attribute__((ext_vector_type(8)));
typedef __bf16 bf16x8 __attribute__((ext_vector_type(8)));
typedef float f32x4 __attribute__((ext_vector_type(4)));

__device__ __forceinline__ u16 f2bf(float f) {
  union { float f; unsigned u; } c; c.f = f;
  unsigned u = c.u;
  return (u16)((u + 0x7fff + ((u >> 16) & 1)) >> 16);
}

// fast exp2: scores are bounded (|S| ~ 4), raw v_exp_f32 is safe (1 ULP)
__device__ __forceinline__ float fexp2(float x) {
  float r; asm("v_exp_f32 %0, %1" : "=v"(r) : "v"(x)); return r;
}

// pack two f32 -> bf16x2 in one instruction (T12 recipe; no builtin on gfx950)
__device__ __forceinline__ u32 cvtpk(float lo, float hi) {
  u32 r;
  asm("v_cvt_pk_bf16_f32 %0, %1, %2" : "=v"(r) : "v"(lo), "v"(hi));
  return r;
}

// async global->LDS, 16B per lane. LDS dest must be wave-uniform base + lane*16.
__device__ __forceinline__ void lds16(const u16* g, u16* l) {
  __builtin_amdgcn_global_load_lds(
      (const __attribute__((address_space(1))) unsigned int*)g,
      (__attribute__((address_space(3))) unsigned int*)l, 16, 0, 0);
}

// SCALE = (1280//8)^-0.5, folded with log2(e); baked into Q-projection weights
#define CEXP (0.07905694150420949f * 1.4426950408889634f)

#define BAR()  do { asm volatile("" ::: "memory"); \
                    __builtin_amdgcn_s_barrier(); \
                    asm volatile("" ::: "memory"); } while (0)
#define VMC(n) asm volatile("s_waitcnt vmcnt(" #n ")" ::: "memory")

// ---------------------------------------------------------------------------
// weight prep only: Wd cast | Wqkv^T (+CEXP on Q rows) | Wup^T
// ---------------------------------------------------------------------------
#define PREP_W (1280 * 256 + 768 * 256 + 1280 * 256)   // 851968 weight elems

__global__ __launch_bounds__(256)
void prep_w(const float* __restrict__ Wd, const float* __restrict__ Wqkv,
            const float* __restrict__ Wup,
            u16* __restrict__ WdC, u16* __restrict__ WqkvT,
            u16* __restrict__ WupT) {
  int id = blockIdx.x * 256 + threadIdx.x;
  if (id < 1280 * 256) {                      // straight cast of Wd
    WdC[id] = f2bf(Wd[id]);
    return;
  }
  id -= 1280 * 256;
  if (id < 768 * 256) {                       // Wqkv^T, scale Q rows by CEXP
    int n = id >> 8, c = id & 255;
    float v = Wqkv[(size_t)c * 768 + n];
    if (n < 256) v *= CEXP;
    WqkvT[id] = f2bf(v);
    return;
  }
  id -= 768 * 256;
  if (id < 1280 * 256) {                      // Wup^T
    int n = id >> 8, c = id & 255;
    WupT[id] = f2bf(Wup[(size_t)c * 1280 + n]);
  }
}

// ---------------------------------------------------------------------------
// Fused: WpT GEMM (60 blocks, latency-bound) + x->bf16 cast (memory-bound).
// ---------------------------------------------------------------------------
__global__ __launch_bounds__(256)
void wpt_xcast(const u16* __restrict__ WqkvT, const u16* __restrict__ WdC,
               u16* __restrict__ WpT,
               const float* __restrict__ X, u16* __restrict__ Xb, int n8)
{
  __shared__ u16 As[128][64];
  __shared__ u16 Bs[128][64];

  if (blockIdx.x >= 60) {                     // ---- x -> bf16 cast ----
    int id = (blockIdx.x - 60) * 256 + threadIdx.x;
    if (id < n8) {
      const float4* src = (const float4*)(X + (size_t)id * 8);
      float4 lo = src[0], hi = src[1];
      u16x8 v;
      v[0]=f2bf(lo.x); v[1]=f2bf(lo.y); v[2]=f2bf(lo.z); v[3]=f2bf(lo.w);
      v[4]=f2bf(hi.x); v[5]=f2bf(hi.y); v[6]=f2bf(hi.z); v[7]=f2bf(hi.w);
      *(u16x8*)(Xb + (size_t)id * 8) = v;
    }
    return;
  }

  // ---- WpT GEMM, M=768 N=1280 K=256 ----
  const int tid  = threadIdx.x;
  const int wave = tid >> 6, lane = tid & 63;
  const int quad = lane >> 4, l16 = lane & 15;
  const int rsw  = l16 & 7;
  const int ssw  = ((lane & 7) ^ (lane >> 3)) << 3;
  const int band = blockIdx.x / 10, nblk = blockIdx.x % 10;
  const int m0 = band * 128, n0 = nblk * 128;
  const int wr = (wave >> 1) * 64, wc = (wave & 1) * 64;
  const int K = 256, N = 1280;

  f32x4 acc[4][4];
#pragma unroll
  for (int i = 0; i < 4; i++)
#pragma unroll
    for (int j = 0; j < 4; j++) acc[i][j] = f32x4{0.f, 0.f, 0.f, 0.f};

  for (int k0 = 0; k0 < K; k0 += 64) {
#pragma unroll
    for (int it = 0; it < 4; it++) {
      int r0 = wave * 32 + it * 8;
      lds16(&WqkvT[(size_t)(m0 + r0 + (lane >> 3)) * K + k0 + ssw],
            &As[r0][0] + lane * 8);
      lds16(&WdC[(size_t)(n0 + r0 + (lane >> 3)) * K + k0 + ssw],
            &Bs[r0][0] + lane * 8);
    }
    __syncthreads();
#pragma unroll
    for (int ks = 0; ks < 64; ks += 32) {
      bf16x8 af[4], bfr[4];
#pragma unroll
      for (int i = 0; i < 4; i++)
        af[i] = *(const bf16x8*)&As[wr + i * 16 + l16][(((ks >> 3) + quad) ^ rsw) << 3];
#pragma unroll
      for (int j = 0; j < 4; j++)
        bfr[j] = *(const bf16x8*)&Bs[wc + j * 16 + l16][(((ks >> 3) + quad) ^ rsw) << 3];
#pragma unroll
      for (int i = 0; i < 4; i++)
#pragma unroll
        for (int j = 0; j < 4; j++)
          acc[i][j] = __builtin_amdgcn_mfma_f32_16x16x32_bf16(af[i], bfr[j], acc[i][j], 0, 0, 0);
    }
    __syncthreads();
  }

#pragma unroll
  for (int i = 0; i < 4; i++)
#pragma unroll
    for (int j = 0; j < 4; j++) {
      int col = n0 + wc + j * 16 + l16;
#pragma unroll
      for (int r = 0; r < 4; r++) {
        int row = m0 + wr + i * 16 + quad * 4 + r;
        WpT[(size_t)row * N + col] = f2bf(acc[i][j][r]);
      }
    }
}

// ---------------------------------------------------------------------------
// GEMM: C[M,N] = A[M,K] * BT[N,K]^T (+bias). m97 structure + content-XOR
// LDS swizzle. 128x128 tile, 4 waves of 64x64, BK=64. Used for the final
// f32-out projection and the AF32 fallback.
// ---------------------------------------------------------------------------
template <int AF32>
__global__ __launch_bounds__(256)
void gemm_bt(const void* __restrict__ Av,
             const u16* __restrict__ BT,
             u16* __restrict__ Cb, float* __restrict__ Cf,
             const float* __restrict__ bias,
             int M, int N, int K)
{
  __shared__ u16 As[128][64];
  __shared__ u16 Bs[128][64];
  const int tid  = threadIdx.x;
  const int wave = tid >> 6, lane = tid & 63;
  const int quad = lane >> 4, l16 = lane & 15;
  const int rsw  = l16 & 7;                 // read-side row XOR
  const int ssw  = ((lane & 7) ^ (lane >> 3)) << 3;  // staging col (pre-swz)

  const int nb = N >> 7, mb = M >> 7;
  int band, nblk;
  if ((mb & 7) == 0) {
    int xcd = blockIdx.x & 7, slot = blockIdx.x >> 3;
    band = xcd + 8 * (slot / nb);
    nblk = slot % nb;
  } else {
    band = blockIdx.x / nb;
    nblk = blockIdx.x % nb;
  }
  const int m0 = band * 128, n0 = nblk * 128;
  const int wr = (wave >> 1) * 64, wc = (wave & 1) * 64;
  const u16*   A16 = (const u16*)Av;
  const float* A32 = (const float*)Av;

  f32x4 acc[4][4];
#pragma unroll
  for (int i = 0; i < 4; i++)
#pragma unroll
    for (int j = 0; j < 4; j++) acc[i][j] = f32x4{0.f, 0.f, 0.f, 0.f};

  for (int k0 = 0; k0 < K; k0 += 64) {
    if constexpr (AF32) {
#pragma unroll
      for (int it = 0; it < 4; it++) {
        int idx = tid + it * 256;
        int r = idx >> 3;
        const float* src = &A32[(size_t)(m0 + r) * K + k0 + ((idx & 7) << 3)];
        float4 lo = *(const float4*)src;
        float4 hi = *(const float4*)(src + 4);
        u16x8 v;
        v[0]=f2bf(lo.x); v[1]=f2bf(lo.y); v[2]=f2bf(lo.z); v[3]=f2bf(lo.w);
        v[4]=f2bf(hi.x); v[5]=f2bf(hi.y); v[6]=f2bf(hi.z); v[7]=f2bf(hi.w);
        *(u16x8*)&As[r][((idx & 7) ^ (r & 7)) << 3] = v;
      }
#pragma unroll
      for (int it = 0; it < 4; it++) {
        int r0 = wave * 32 + it * 8;
        lds16(&BT[(size_t)(n0 + r0 + (lane >> 3)) * K + k0 + ssw],
              &Bs[r0][0] + lane * 8);
      }
    } else {
#pragma unroll
      for (int it = 0; it < 4; it++) {
        int r0 = wave * 32 + it * 8;
        lds16(&A16[(size_t)(m0 + r0 + (lane >> 3)) * K + k0 + ssw],
              &As[r0][0] + lane * 8);
        lds16(&BT[(size_t)(n0 + r0 + (lane >> 3)) * K + k0 + ssw],
              &Bs[r0][0] + lane * 8);
      }
    }
    __syncthreads();
#pragma unroll
    for (int ks = 0; ks < 64; ks += 32) {
      bf16x8 af[4], bfr[4];
#pragma unroll
      for (int i = 0; i < 4; i++)
        af[i] = *(const bf16x8*)&As[wr + i * 16 + l16][(((ks >> 3) + quad) ^ rsw) << 3];
#pragma unroll
      for (int j = 0; j < 4; j++)
        bfr[j] = *(const bf16x8*)&Bs[wc + j * 16 + l16][(((ks >> 3) + quad) ^ rsw) << 3];
#pragma unroll
      for (int i = 0; i < 4; i++)
#pragma unroll
        for (int j = 0; j < 4; j++)
          acc[i][j] = __builtin_amdgcn_mfma_f32_16x16x32_bf16(af[i], bfr[j], acc[i][j], 0, 0, 0);
    }
    __syncthreads();
  }

  // epilogue: C/D layout col=lane&15, row=quad*4+reg
#pragma unroll
  for (int i = 0; i < 4; i++) {
#pragma unroll
    for (int j = 0; j < 4; j++) {
      int col = n0 + wc + j * 16 + l16;
      float bv = bias ? bias[col] : 0.0f;
#pragma unroll
      for (int r = 0; r < 4; r++) {
        int row = m0 + wr + i * 16 + quad * 4 + r;
        float v = acc[i][j][r] + bv;
        if (Cf) Cf[(size_t)row * N + col] = v;
        else    Cb[(size_t)row * N + col] = f2bf(v);
      }
    }
  }
}

// ---------------------------------------------------------------------------
// qkv-GEMM, 8-phase schedule, 256x256 tile, 512 threads, BK=64, 128 KiB LDS.
// Epilogue writes PACKED per-(b,chunk,head) panels instead of row-major qkv:
//   nblk=0 -> qT[gh][token][32d]   (same store count/coalescing as before)
//   nblk=1 -> kT[gh][token][32d]   (attn K-staging becomes linear 4KB DMA)
//   nblk=2 -> vT[gh][32d][1024 key-slots] via LDS transpose (sigma key-perm
//             baked in; replaces the standalone vtrans kernel).
// R8 fix: V store stage partition is for 512 threads (hd0=tid>>3 in 0..63,
// u<4, hd=u*64+hd0 covers 0..255 exactly once). R7 used a 256-thread
// partition (u*32+hd0, u<8) -> hd up to 287: OOB LDS reads + writes into
// the NEXT gh panel (head=8) -> absmax 0.12 corruption.
// ---------------------------------------------------------------------------
#define LDA_(d, ib) { _Pragma("unroll") for (int i = 0; i < 4; i++) \
  _Pragma("unroll") for (int ks = 0; ks < 2; ks++) \
    af[i*2+ks] = *(const bf16x8*)&As[d][wm][(ib+i)*16 + l16][((ks*4+quad) ^ rsw) << 3]; }

#define LDB_(d, dst, jp) { _Pragma("unroll") for (int j = 0; j < 2; j++) \
  _Pragma("unroll") for (int ks = 0; ks < 2; ks++) \
    dst[j*2+ks] = *(const bf16x8*)&Bs[d][bh][br + (jp*2+j)*16 + l16][((ks*4+quad) ^ rsw) << 3]; }

#define MM_(ib, jp, breg) { __builtin_amdgcn_s_setprio(1); \
  _Pragma("unroll") for (int i = 0; i < 4; i++) \
  _Pragma("unroll") for (int j = 0; j < 2; j++) \
  _Pragma("unroll") for (int ks = 0; ks < 2; ks++) \
    acc[ib+i][jp*2+j] = __builtin_amdgcn_mfma_f32_16x16x32_bf16( \
        af[i*2+ks], breg[j*2+ks], acc[ib+i][jp*2+j], 0, 0, 0); \
  __builtin_amdgcn_s_setprio(0); }

__global__ __launch_bounds__(512, 2)
void gemm_qkv(const u16* __restrict__ A16, const u16* __restrict__ BT,
              u16* __restrict__ qT, u16* __restrict__ kT,
              u16* __restrict__ vT, int M, int N, int K)
{
  __shared__ __align__(16) u16 SH[2][2][2][128][64];  // [A/B][dbuf][half][r][c]
  auto& As = SH[0];
  auto& Bs = SH[1];
  const int tid  = threadIdx.x;
  const int wave = tid >> 6, lane = tid & 63;
  const int quad = lane >> 4, l16 = lane & 15;
  const int wm = wave >> 2, wn = wave & 3;   // 2 x 4 wave grid
  const int bh = wn >> 1, br = (wn & 1) * 64;
  const int rsw = l16 & 7;

  const int nb = N >> 8;
  const int xcd = blockIdx.x & 7, slot = blockIdx.x >> 3;
  const int band = xcd + 8 * (slot / nb);
  const int nblk = slot % nb;
  const int m0 = band * 256, n0 = nblk * 256;
  const int NT = K >> 6;                     // 64-wide K tiles (even, >=4)

  const int srow = tid >> 3;                 // 0..63
  const int scol = ((tid & 7) ^ (srow & 7)) << 3;  // pre-swizzled global col

  auto stageA = [&](int t, int h) {
    const int d = t & 1;
    const size_t g = (size_t)(m0 + h * 128 + srow) * K + (t << 6) + scol;
    lds16(&A16[g], &As[d][h][0][0] + tid * 8);
    lds16(&A16[g + (size_t)64 * K], &As[d][h][64][0] + tid * 8);
  };
  auto stageB = [&](int t, int h) {
    const int d = t & 1;
    const size_t g = (size_t)(n0 + h * 128 + srow) * K + (t << 6) + scol;
    lds16(&BT[g], &Bs[d][h][0][0] + tid * 8);
    lds16(&BT[g + (size_t)64 * K], &Bs[d][h][64][0] + tid * 8);
  };

  bf16x8 af[8], b0[4], b1[4];
  f32x4 acc[8][4];
#pragma unroll
  for (int i = 0; i < 8; i++)
#pragma unroll
    for (int j = 0; j < 4; j++) acc[i][j] = f32x4{0.f, 0.f, 0.f, 0.f};

  // prologue: tile0 complete + tile1 A-half0
  stageA(0, 0); stageA(0, 1); stageB(0, 0); stageB(0, 1); stageA(1, 0);
  VMC(2);
  BAR();

  const int nIter = NT >> 1;
  for (int it = 0; it < nIter; ++it) {
    const int t0 = it * 2, t1 = t0 + 1;
    const bool more  = (t0 + 2 < NT);
    const bool more1 = (t1 + 2 < NT);

    // ---- dbuf0 (tile t0) ----
    LDA_(0, 0); LDB_(0, b0, 0);
    stageA(t1, 1);
    BAR(); MM_(0, 0, b0); BAR();
    LDB_(0, b1, 1);
    stageB(t1, 0);
    BAR(); MM_(0, 1, b1); BAR();
    LDA_(0, 4);
    stageB(t1, 1);
    BAR(); MM_(4, 1, b1); BAR();
    if (more) stageA(t0 + 2, 0);
    BAR(); MM_(4, 0, b0);
    if (more) { VMC(2); } else { VMC(0); }
    BAR();

    // ---- dbuf1 (tile t1) ----
    LDA_(1, 0); LDB_(1, b0, 0);
    if (more) stageA(t0 + 2, 1);
    BAR(); MM_(0, 0, b0); BAR();
    LDB_(1, b1, 1);
    if (more) stageB(t0 + 2, 0);
    BAR(); MM_(0, 1, b1); BAR();
    LDA_(1, 4);
    if (more) stageB(t0 + 2, 1);
    BAR(); MM_(4, 1, b1); BAR();
    if (more1) stageA(t1 + 2, 0);
    BAR(); MM_(4, 0, b0);
    if (it + 1 < nIter) {
      if (more1) { VMC(2); } else { VMC(0); }
      BAR();
    }
  }

  const int b_ = m0 >> 12, chunk_ = (m0 >> 10) & 3;
  const int ghb = (b_ * 4 + chunk_) * 8;

  if (n0 == 512) {
    // ---- V: transpose through the (now free) 128 KiB LDS into vT ----
    u16* T = &SH[0][0][0][0][0];             // [vcol][256 tokens], XOR-swz
    BAR();                                   // all waves done reading LDS
#pragma unroll
    for (int i = 0; i < 8; i++)
#pragma unroll
      for (int j = 0; j < 4; j++) {
        const int vcol = wn * 64 + j * 16 + l16;          // head*32+d
        const int tok4 = (wm * 128 + i * 16 + quad * 4) ^ ((vcol & 7) << 2);
        uint2 w;
        w.x = cvtpk(acc[i][j][0], acc[i][j][1]);
        w.y = cvtpk(acc[i][j][2], acc[i][j][3]);
        *(uint2*)&T[vcol * 256 + tok4] = w;
      }
    __syncthreads();
    const int ktb = (m0 & 1023) >> 6;
    const int s   = tid & 7;
    const int hd0 = tid >> 3;                // 0..63 (512 threads)
#pragma unroll
    for (int u = 0; u < 4; u++) {
      const int hd = u * 64 + hd0;           // 0..255, each exactly once
      const int head = hd >> 5, d = hd & 31;
      const int x = (hd & 7) << 2;
      const size_t gb = (size_t)(ghb + head) * 32768 + (size_t)d * 1024 + s * 8;
#pragma unroll
      for (int kt4 = 0; kt4 < 4; kt4++) {
        const int base = kt4 * 64 + ((s >> 2) << 5) + ((s & 3) << 2);
        u16x4 lo = *(const u16x4*)&T[hd * 256 + (base ^ x)];
        u16x4 hi = *(const u16x4*)&T[hd * 256 + ((base + 16) ^ x)];
        u16x8 o8;
        o8[0]=lo[0]; o8[1]=lo[1]; o8[2]=lo[2]; o8[3]=lo[3];
        o8[4]=hi[0]; o8[5]=hi[1]; o8[6]=hi[2]; o8[7]=hi[3];
        *(u16x8*)&vT[gb + (size_t)(ktb + kt4) * 64] = o8;
      }
    }
  } else {
    // ---- Q/K: packed scalar stores (same count/coalescing as row-major) ----
    u16* P = (n0 == 0) ? qT : kT;
    const int tic0 = (m0 & 1023) + wm * 128 + quad * 4;
#pragma unroll
    for (int i = 0; i < 8; i++)
#pragma unroll
      for (int j = 0; j < 4; j++) {
        const int c255 = wn * 64 + j * 16 + l16;
        const int head = c255 >> 5, d = c255 & 31;
        u16* Pg = P + (size_t)(ghb + head) * 32768 + d;
#pragma unroll
        for (int r = 0; r < 4; r++) {
          const int tic = tic0 + i * 16 + r;
          Pg[(size_t)tic * 32] = f2bf(acc[i][j][r]);
        }
      }
  }
}

// ---------------------------------------------------------------------------
// Fallback-only repack: row-major qkv -> packed qT/kT/vT (perf-irrelevant).
// ---------------------------------------------------------------------------
__global__ __launch_bounds__(256)
void repack_fb(const u16* __restrict__ qkv, u16* __restrict__ qT,
               u16* __restrict__ kT, u16* __restrict__ vT)
{
  int id = blockIdx.x * 256 + threadIdx.x;   // token*8 + head
  int tok = id >> 3, head = id & 7;
  int b = tok >> 12, chunk = (tok >> 10) & 3, tic = tok & 1023;
  int gh = (b * 4 + chunk) * 8 + head;
  int kt = tic >> 6, k64 = tic & 63, b32 = k64 >> 5, k32 = k64 & 31;
  int s = b32 * 4 + ((k32 >> 2) & 3);
  int j = (k32 & 3) | ((k32 >> 4) << 2);
  size_t src = (size_t)tok * 768 + head * 32;
  for (int d = 0; d < 32; d++) {
    qT[(size_t)gh * 32768 + (size_t)tic * 32 + d] = qkv[src + d];
    kT[(size_t)gh * 32768 + (size_t)tic * 32 + d] = qkv[src + 256 + d];
    vT[(size_t)gh * 32768 + (size_t)d * 1024 + kt * 64 + s * 8 + j] = qkv[src + 512 + d];
  }
}

// ---------------------------------------------------------------------------
// Block-diagonal attention on packed panels. Q pre-scaled by SCALE*log2e.
// K/V staged via global_load_lds (K a LINEAR 4KB DMA per tile) into a
// 4-buffer ring, 2 tiles ahead, counted vmcnt(2). P never touches LDS;
// denominator via ones-B MFMA. gid = qb*128+g pins the 8 K/V-sharing
// qb-blocks to one XCD.
// ---------------------------------------------------------------------------
__global__ __launch_bounds__(256)
void attn_kernel(const u16* __restrict__ qT, const u16* __restrict__ kT,
                 const u16* __restrict__ vT, u16* __restrict__ o)
{
  __shared__ __align__(16) u16 Ks[4][64][32];    // keys [key][d]
  __shared__ __align__(16) u16 VTs[4][32][64];   // V^T [d][key-slot] (swz)

  const int tid  = threadIdx.x;
  const int wave = tid >> 6, lane = tid & 63;
  const int quad = lane >> 4, l16 = lane & 15;
  const int gid   = blockIdx.x;        // 0..1023
  const int qb    = gid >> 7;          // 0..7
  const int g     = gid & 127;         // group: shares K/V, pinned to XCD g&7
  const int head  = g >> 4;            // 0..7
  const int chunk = (g >> 2) & 3;      // 0..3
  const int b     = g & 3;             // 0..3
  const int gh    = (b * 4 + chunk) * 8 + head;
  const size_t rowbase = (size_t)b * 4096 + chunk * 1024;
  const int tok0 = qb * 128 + wave * 32;

  const int vr   = tid >> 3;                     // d row 0..31
  const int vs   = tid & 7;                      // LDS slot'
  const int vsl  = (vs ^ (vr & 7)) << 3;         // content offset (XOR swz)
  const size_t vbase = (size_t)gh * 32768 + (size_t)vr * 1024 + vsl;
  const size_t kbase = (size_t)gh * 32768;

  auto stageKV = [&](int kb, int buf) {
    lds16(&kT[kbase + kb * 2048 + tid * 8], &Ks[buf][0][0] + tid * 8);
    lds16(&vT[vbase + (size_t)kb * 64], &VTs[buf][0][0] + tid * 8);
  };

  stageKV(0, 0);

  bf16x8 qf[2];
#pragma unroll
  for (int qt = 0; qt < 2; qt++)
    qf[qt] = *(const bf16x8*)&qT[kbase + (size_t)(tok0 + qt * 16 + l16) * 32 + quad * 8];

  stageKV(1, 1);

  // all-ones bf16 B-fragment for the denominator MFMA
  bf16x8 onesb;
  {
    union { u16x8 u; bf16x8 v; } c;
#pragma unroll
    for (int i = 0; i < 8; i++) c.u[i] = 0x3F80;
    onesb = c.v;
  }

  f32x4 Oacc[2][2], Osum[2];
#pragma unroll
  for (int qt = 0; qt < 2; qt++) {
    Osum[qt] = f32x4{0.f, 0.f, 0.f, 0.f};
#pragma unroll
    for (int nd = 0; nd < 2; nd++) Oacc[qt][nd] = f32x4{0.f, 0.f, 0.f, 0.f};
  }

  VMC(2);          // buf0 landed (stage(1) may stay in flight)
  BAR();

  for (int kb = 0; kb < 16; kb++) {
    const int cur = kb & 3;
    if (kb + 2 < 16) stageKV(kb + 2, (kb + 2) & 3);

    bf16x8 kf[4];
#pragma unroll
    for (int kt = 0; kt < 4; kt++)
      kf[kt] = *(const bf16x8*)&Ks[cur][kt * 16 + l16][quad * 8];

    f32x4 ST[4][2];
    __builtin_amdgcn_s_setprio(1);
#pragma unroll
    for (int kt = 0; kt < 4; kt++)
#pragma unroll
      for (int qt = 0; qt < 2; qt++)
        ST[kt][qt] = __builtin_amdgcn_mfma_f32_16x16x32_bf16(kf[kt], qf[qt], f32x4{0.f,0.f,0.f,0.f}, 0, 0, 0);
    __builtin_amdgcn_s_setprio(0);

    // softmax weights, packed lane-locally (no LDS round-trip, no lsum adds)
    u32 pw[2][4][2];
#pragma unroll
    for (int qt = 0; qt < 2; qt++)
#pragma unroll
      for (int kt = 0; kt < 4; kt++) {
        float p0 = fexp2(ST[kt][qt][0]);
        float p1 = fexp2(ST[kt][qt][1]);
        float p2 = fexp2(ST[kt][qt][2]);
        float p3 = fexp2(ST[kt][qt][3]);
        pw[qt][kt][0] = cvtpk(p0, p1);
        pw[qt][kt][1] = cvtpk(p2, p3);
      }

#pragma unroll
    for (int ks = 0; ks < 2; ks++) {
      bf16x8 vf[2];
#pragma unroll
      for (int nd = 0; nd < 2; nd++)
        vf[nd] = *(const bf16x8*)&VTs[cur][nd * 16 + l16][((ks * 4 + quad) ^ (l16 & 7)) << 3];
      __builtin_amdgcn_s_setprio(1);
#pragma unroll
      for (int qt = 0; qt < 2; qt++) {
        union { u32 w[4]; bf16x8 v; } pu;
        pu.w[0] = pw[qt][2 * ks][0];
        pu.w[1] = pw[qt][2 * ks][1];
        pu.w[2] = pw[qt][2 * ks + 1][0];
        pu.w[3] = pw[qt][2 * ks + 1][1];
#pragma unroll
        for (int nd = 0; nd < 2; nd++)
          Oacc[qt][nd] = __builtin_amdgcn_mfma_f32_16x16x32_bf16(pu.v, vf[nd], Oacc[qt][nd], 0, 0, 0);
        Osum[qt] = __builtin_amdgcn_mfma_f32_16x16x32_bf16(pu.v, onesb, Osum[qt], 0, 0, 0);
      }
      __builtin_amdgcn_s_setprio(0);
    }

    if (kb < 15) {
      if (kb + 2 < 16) { VMC(2); } else { VMC(0); }
      BAR();
    }
  }

  // epilogue: Osum[qt][r] is the denominator for this lane's own row
#pragma unroll
  for (int qt = 0; qt < 2; qt++)
#pragma unroll
    for (int r = 0; r < 4; r++) {
      float inv = 1.0f / Osum[qt][r];
      size_t row = rowbase + tok0 + qt * 16 + quad * 4 + r;
#pragma unroll
      for (int nd = 0; nd < 2; nd++) {
        int col = head * 32 + nd * 16 + l16;
        o[row * 256 + col] = f2bf(Oacc[qt][nd][r] * inv);
      }
    }
}

// ---------------------------------------------------------------------------
extern "C" void kernel_launch(void* const* d_in, const int* in_sizes, int n_in,
                              void* d_out, int out_size, void* d_ws, size_t ws_size,
                              hipStream_t stream)
{
  const float* x    = (const float*)d_in[0];
  const float* Wd   = (const float*)d_in[1];
  const float* Wqkv = (const float*)d_in[2];
  const float* Wup  = (const float*)d_in[3];
  const float* bup  = (const float*)d_in[4];
  float* out = (float*)d_out;

  const int M = 4 * 4096;  // 16384 tokens
  const size_t PANEL = (size_t)128 * 32768;  // 4194304 u16 per packed panel

  // workspace (u16 elems): WdC | WqkvT | WupT | WpT | qT|kT|vT | ob | xb
  u16* WdC   = (u16*)d_ws;              // Wd cast      [1280][256]
  u16* WqkvT = WdC   + 1280 * 256;      // Wqkv^T       [768][256] (Q rows *CEXP)
  u16* WupT  = WqkvT + 768 * 256;       // Wup^T        [1280][256]
  u16* WpT   = WupT  + 1280 * 256;      // (Wd@Wqkv)^T  [768][1280]
  u16* qT    = WpT   + 768 * 1280;      // packed Q [128 gh][1024 tok][32 d]
  u16* kT    = qT    + PANEL;           // packed K (same layout)
  u16* vT    = kT    + PANEL;           // packed V [128 gh][32 d][1024 slots]
  u16* ob    = vT    + PANEL;           // [16384][256]
  u16* xb    = ob    + (size_t)M * 256; // [16384][1280] bf16 cast of x

  const size_t need = ((size_t)(1280*256 + 768*256 + 1280*256 + 768*1280)
                       + (size_t)M * (768 + 256 + 1280)) * sizeof(u16);
  const bool use_xb = ws_size >= need;  // ws_size constant across calls

  // weight prep (small, fast)
  prep_w<<<(PREP_W + 255) / 256, 256, 0, stream>>>(
      Wd, Wqkv, Wup, WdC, WqkvT, WupT);

  // fused: WpT GEMM (60 blocks) overlapped with x->bf16 cast
  const int n8 = use_xb ? (M * 1280 / 8) : 0;
  wpt_xcast<<<60 + (n8 + 255) / 256, 256, 0, stream>>>(
      WqkvT, WdC, WpT, x, xb, n8);

  const u16 *aq, *ak, *av;
  if (use_xb) {
    // qkv projection with fused packed-layout epilogue (vtrans eliminated)
    gemm_qkv<<<dim3((768 / 256) * (M / 256)), 512, 0, stream>>>(
        xb, WpT, qT, kT, vT, M, 768, 1280);
    aq = qT; ak = kT; av = vT;
  } else {
    // fallback: row-major qkv into the panel region, repack into d_out scratch
    u16* qkv = qT;                       // 12.6M u16 region reused
    gemm_bt<1><<<dim3((768 / 128) * (M / 128)), 256, 0, stream>>>(
        (const void*)x, WpT, qkv, nullptr, nullptr, M, 768, 1280);
    u16* s0 = (u16*)d_out;               // 24 MB scratch inside the 84 MB out
    repack_fb<<<(M * 8) / 256, 256, 0, stream>>>(qkv, s0, s0 + PANEL, s0 + 2 * PANEL);
    aq = s0; ak = s0 + PANEL; av = s0 + 2 * PANEL;
  }

  // block-diagonal attention (XCD-grouped 1-D grid)
  attn_kernel<<<dim3(1024), 256, 0, stream>>>(aq, ak, av, ob);

  // out = o @ Wup + bup (f32 out) — 128^2 swizzled path
  gemm_bt<0><<<dim3((1280 / 128) * (M / 128)), 256, 0, stream>>>(
      (const void*)ob, WupT, nullptr, out, bup, M, 1280, 256);
}